// Round 9
// baseline (349.726 us; speedup 1.0000x reference)
//
#include <hip/hip_runtime.h>
#include <stdint.h>

#define K_DIM 4096
#define N_DIM 11008
#define WORDS_N 1376          // N_DIM / 8 packed words
#define BM 128
#define BN 256
#define BK 64
#define ASTR 72               // As row stride in fp16 elems
#define WSTR 68               // fused-fallback Wq stride (ints)

typedef _Float16 f16x2 __attribute__((ext_vector_type(2)));
typedef _Float16 f16x8 __attribute__((ext_vector_type(8)));
typedef float    f32x4 __attribute__((ext_vector_type(4)));
typedef float    f32x8 __attribute__((ext_vector_type(8)));
typedef int      int4v __attribute__((ext_vector_type(4)));
typedef int      int2v __attribute__((ext_vector_type(2)));
typedef unsigned short ushort;
typedef unsigned int u32;

__device__ __forceinline__ f16x2 dq2(int wa, int wb, int shf, f16x2 s2, f16x2 c2) {
    u32 t0 = ((u32)wa >> shf) & 0xFu;
    u32 t1 = ((u32)wb >> shf) & 0xFu;
    u32 h  = 0x64006400u | t0 | (t1 << 16);
    f16x2 q = __builtin_bit_cast(f16x2, h);
    q = q - (f16x2)((_Float16)1024.0f);
    return q * s2 + c2;
}

// ---- pre-pass 1: x f32 -> fp16 (values exactly fp16-representable) ----
__global__ __launch_bounds__(256)
void cvt_x_kernel(const float* __restrict__ x, ushort* __restrict__ xf, int n8) {
    for (int i = blockIdx.x * 256 + threadIdx.x; i < n8; i += gridDim.x * 256) {
        f32x4 a = *(const f32x4*)(x + (size_t)i * 8);
        f32x4 b = *(const f32x4*)(x + (size_t)i * 8 + 4);
        int4v o;
        o[0] = __builtin_bit_cast(int, __builtin_amdgcn_cvt_pkrtz(a[0], a[1]));
        o[1] = __builtin_bit_cast(int, __builtin_amdgcn_cvt_pkrtz(a[2], a[3]));
        o[2] = __builtin_bit_cast(int, __builtin_amdgcn_cvt_pkrtz(b[0], b[1]));
        o[3] = __builtin_bit_cast(int, __builtin_amdgcn_cvt_pkrtz(b[2], b[3]));
        *(int4v*)(xf + (size_t)i * 8) = o;
    }
}

// ---- pre-pass 2: dequant qweight -> W16[n][k] fp16 row-major ----
// block = 64n x 64k tile. LDS-transposed raw words, per-thread fixed nibble,
// f32 math + RNE f16 (identical single-rounding to the reference).
__global__ __launch_bounds__(256)
void dequant_w_kernel(const int* __restrict__ qw,
                      const int* __restrict__ qz,
                      const float* __restrict__ sc,
                      _Float16* __restrict__ W16)
{
    __shared__ __align__(16) int Wq[8 * WSTR];   // [word][k], 64 k
    const int t  = threadIdx.x;
    const int w0 = blockIdx.x * 8;               // word-col base (172 blocks)
    const int n0 = blockIdx.x * 64;
    const int k0 = blockIdx.y * 64;              // 64 blocks

    // load 64k x 8w raw words (int2 per thread), write transposed
    {
        const int k  = t >> 2;
        const int wp = (t & 3) * 2;
        const int2v v = *(const int2v*)(qw + (size_t)(k0 + k) * WORDS_N + w0 + wp);
        Wq[(wp + 0) * WSTR + k] = v[0];
        Wq[(wp + 1) * WSTR + k] = v[1];
    }
    __syncthreads();

    const int n   = t & 63;
    const int oc0 = t >> 6;                      // k-octet 0..3 (+4 second pass)
    const int w   = n >> 3;
    const int j   = n & 7;
    const int shf = ((j & 1) << 4) + ((j >> 1) << 2);   // AWQ interleave
    const int g   = k0 >> 7;                     // group fixed per 64-k tile

    const float s  = sc[(size_t)g * N_DIM + n0 + n];
    const int   zq = (qz[(size_t)g * WORDS_N + w0 + w] >> shf) & 0xF;
    const float nz = -(float)zq * s;

    #pragma unroll
    for (int oo = 0; oo < 2; ++oo) {
        const int oc = oc0 + oo * 4;
        const int4v lo = *(const int4v*)&Wq[w * WSTR + oc * 8];
        const int4v hi = *(const int4v*)&Wq[w * WSTR + oc * 8 + 4];
        f16x8 h;
        #pragma unroll
        for (int r = 0; r < 4; ++r)
            h[r] = (_Float16)((float)((lo[r] >> shf) & 0xF) * s + nz);
        #pragma unroll
        for (int r = 0; r < 4; ++r)
            h[4 + r] = (_Float16)((float)((hi[r] >> shf) & 0xF) * s + nz);
        *(f16x8*)(W16 + (size_t)(n0 + n) * K_DIM + k0 + oc * 8) = h;
    }
}

// ---- main GEMM: A via LDS (round-7 2-barrier), B fragments direct from W16 ----
__global__ __launch_bounds__(256, 2)
void awq_gemm_split(const ushort* __restrict__ x16,
                    const _Float16* __restrict__ W16,
                    const float* __restrict__ bias,
                    float* __restrict__ out,
                    int M, int mtiles, int nwg)
{
    __shared__ __align__(16) _Float16 As[BM * ASTR];

    const int tid  = threadIdx.x;
    const int lane = tid & 63;
    const int wid  = tid >> 6;

    // bijective XCD swizzle (m204): consecutive logical ids -> same XCD.
    // logical id g enumerates by-within-bx so same-bx blocks (sharing B panels)
    // cluster on one XCD's L2.
    int h = blockIdx.x;
    const int q_ = nwg >> 3, r_ = nwg & 7;
    const int xcd = h & 7, pos = h >> 3;
    const int g = (xcd < r_ ? xcd * (q_ + 1) : r_ * (q_ + 1) + (xcd - r_) * q_) + pos;
    const int bx = g / mtiles;
    const int by = g - bx * mtiles;

    const int bn0 = bx * BN;
    const int bm0 = by * BM;
    const int wn0 = wid * 64;   // wave owns 128 rows x 64 cols

    // A staging: 4 rows of 8 fp16 per thread
    const int a_row = tid >> 3;
    const int a_col = (tid & 7) * 8;

    // per-bn B row pointers (col fixed per lane)
    const _Float16* bp[4];
    #pragma unroll
    for (int bn = 0; bn < 4; ++bn)
        bp[bn] = W16 + (size_t)(bn0 + wn0 + bn * 16 + (lane & 15)) * K_DIM;

    f32x4 acc[8][4];
    #pragma unroll
    for (int i = 0; i < 8; ++i)
        #pragma unroll
        for (int j = 0; j < 4; ++j)
            acc[i][j] = (f32x4){0.f, 0.f, 0.f, 0.f};

    int4v aReg[4];
#define LOAD_A(K0)                                                                  \
    {                                                                               \
        _Pragma("unroll")                                                           \
        for (int i = 0; i < 4; ++i) {                                               \
            int row = bm0 + a_row + i * 32;                                         \
            if (row < M)                                                            \
                aReg[i] = *(const int4v*)(x16 + (size_t)row * K_DIM + (K0) + a_col);\
            else                                                                    \
                aReg[i] = (int4v){0, 0, 0, 0};                                      \
        }                                                                           \
    }

    LOAD_A(0);

    const int NT = K_DIM / BK;  // 64
    for (int t = 0; t < NT; ++t) {
        const int k0 = t * BK;

        __syncthreads();
        #pragma unroll
        for (int i = 0; i < 4; ++i)
            *(int4v*)&As[(a_row + i * 32) * ASTR + a_col] = aReg[i];
        __syncthreads();

        if (t + 1 < NT) LOAD_A(k0 + BK);

        // B fragments: direct global b128 (L2/L3-resident), no LDS, no dequant
        f16x8 bf[2][4];
        #pragma unroll
        for (int ks = 0; ks < 2; ++ks) {
            const int kk = k0 + ks * 32 + (lane >> 4) * 8;
            #pragma unroll
            for (int bn = 0; bn < 4; ++bn)
                bf[ks][bn] = *(const f16x8*)(bp[bn] + kk);
        }

        __builtin_amdgcn_s_setprio(1);
        #pragma unroll
        for (int ks = 0; ks < 2; ++ks) {
            const int kk = ks * 32 + (lane >> 4) * 8;
            f16x8 af[8];
            #pragma unroll
            for (int am = 0; am < 8; ++am)
                af[am] = *(const f16x8*)&As[(am * 16 + (lane & 15)) * ASTR + kk];
            #pragma unroll
            for (int bn = 0; bn < 4; ++bn)
                #pragma unroll
                for (int am = 0; am < 8; ++am)
                    acc[am][bn] = __builtin_amdgcn_mfma_f32_16x16x32_f16(
                        af[am], bf[ks][bn], acc[am][bn], 0, 0, 0);
        }
        __builtin_amdgcn_s_setprio(0);
    }

    #pragma unroll
    for (int bn = 0; bn < 4; ++bn) {
        const int col = bn0 + wn0 + bn * 16 + (lane & 15);
        const float b_f = bias[col];
        #pragma unroll
        for (int am = 0; am < 8; ++am) {
            const int row_base = bm0 + am * 16 + ((lane >> 4) << 2);
            #pragma unroll
            for (int r = 0; r < 4; ++r) {
                const int row = row_base + r;
                if (row < M)
                    out[(size_t)row * N_DIM + col] = acc[am][bn][r] + b_f;
            }
        }
    }
#undef LOAD_A
}

// ---- fallback: round-7 fused kernel (proven; used only if ws too small) ----
template <bool XF16>
__global__ __launch_bounds__(256, 2)
void awq_gemm_fused(const void* __restrict__ xin,
                    const int* __restrict__ qw,
                    const int* __restrict__ qz,
                    const float* __restrict__ sc,
                    const float* __restrict__ bias,
                    float* __restrict__ out,
                    int M)
{
    __shared__ __align__(16) _Float16 As[BM * ASTR];
    __shared__ __align__(16) int Wq[32 * WSTR];

    const int tid  = threadIdx.x;
    const int lane = tid & 63;
    const int wid  = tid >> 6;
    const int bn0 = blockIdx.x * BN;
    const int bm0 = blockIdx.y * BM;
    const int w0  = bn0 >> 3;
    const int wn0 = wid * 64;
    const int a_row = tid >> 3;
    const int a_col = (tid & 7) * 8;
    const int b_krow = tid >> 2;
    const int b_wg   = (tid & 3) * 4;

    int n_loc[4], w_loc[4], shf[4];
    #pragma unroll
    for (int bn = 0; bn < 4; ++bn) {
        n_loc[bn] = wn0 + bn * 16 + (lane & 15);
        w_loc[bn] = n_loc[bn] >> 3;
        int j = n_loc[bn] & 7;
        shf[bn] = ((j & 1) << 4) + ((j >> 1) << 2);
    }
    f16x2 s2[4], c2[4];
    f32x4 acc[8][4];
    #pragma unroll
    for (int i = 0; i < 8; ++i)
        #pragma unroll
        for (int j = 0; j < 4; ++j)
            acc[i][j] = (f32x4){0.f, 0.f, 0.f, 0.f};
    int4v aReg16[4];
    f32x8 aReg32[4];
    int4v bReg[2];
    const ushort* x16 = (const ushort*)xin;
    const float*  x32 = (const float*)xin;

#define LOAD_TILE(K0)                                                                  \
    {                                                                                  \
        _Pragma("unroll")                                                              \
        for (int i = 0; i < 4; ++i) {                                                  \
            int row = bm0 + a_row + i * 32;                                            \
            if constexpr (XF16) {                                                      \
                if (row < M)                                                           \
                    aReg16[i] = *(const int4v*)(x16 + (size_t)row * K_DIM + (K0) + a_col); \
                else aReg16[i] = (int4v){0, 0, 0, 0};                                  \
            } else {                                                                   \
                if (row < M)                                                           \
                    aReg32[i] = *(const f32x8*)(x32 + (size_t)row * K_DIM + (K0) + a_col); \
                else aReg32[i] = (f32x8){0.f,0.f,0.f,0.f,0.f,0.f,0.f,0.f};             \
            }                                                                          \
        }                                                                              \
        bReg[0] = *(const int4v*)(qw + (size_t)((K0) + b_krow) * WORDS_N + w0 + b_wg);      \
        bReg[1] = *(const int4v*)(qw + (size_t)((K0) + b_krow) * WORDS_N + w0 + b_wg + 16); \
    }

    LOAD_TILE(0);
    const int NT = K_DIM / BK;
    for (int t = 0; t < NT; ++t) {
        const int k0 = t * BK;
        __syncthreads();
        #pragma unroll
        for (int i = 0; i < 4; ++i) {
            if constexpr (XF16) {
                *(int4v*)&As[(a_row + i * 32) * ASTR + a_col] = aReg16[i];
            } else {
                f16x8 hh;
                #pragma unroll
                for (int r = 0; r < 4; ++r) {
                    f16x2 p = __builtin_bit_cast(f16x2,
                        __builtin_amdgcn_cvt_pkrtz(aReg32[i][2*r], aReg32[i][2*r+1]));
                    hh[2*r] = p[0]; hh[2*r+1] = p[1];
                }
                *(f16x8*)&As[(a_row + i * 32) * ASTR + a_col] = hh;
            }
        }
        #pragma unroll
        for (int c = 0; c < 4; ++c) {
            Wq[(b_wg + c) * WSTR + b_krow]      = bReg[0][c];
            Wq[(b_wg + 16 + c) * WSTR + b_krow] = bReg[1][c];
        }
        __syncthreads();
        if (t + 1 < NT) LOAD_TILE(k0 + BK);
        if ((t & 1) == 0) {
            const int gg = k0 >> 7;
            #pragma unroll
            for (int bn = 0; bn < 4; ++bn) {
                float s = sc[(size_t)gg * N_DIM + bn0 + n_loc[bn]];
                int zq  = (qz[(size_t)gg * WORDS_N + w0 + w_loc[bn]] >> shf[bn]) & 0xF;
                _Float16 sh = (_Float16)s;
                _Float16 nz = (_Float16)(-(float)zq * s);
                s2[bn] = (f16x2){sh, sh};
                c2[bn] = (f16x2){nz, nz};
            }
        }
        #pragma unroll
        for (int ks = 0; ks < 2; ++ks) {
            const int kk = ks * 32 + (lane >> 4) * 8;
            f16x8 af[8];
            #pragma unroll
            for (int am = 0; am < 8; ++am)
                af[am] = *(const f16x8*)&As[(am * 16 + (lane & 15)) * ASTR + kk];
            #pragma unroll
            for (int bn = 0; bn < 4; ++bn) {
                const int4v lo = *(const int4v*)&Wq[w_loc[bn] * WSTR + kk];
                const int4v hi = *(const int4v*)&Wq[w_loc[bn] * WSTR + kk + 4];
                f16x8 bfr;
                f16x2 p;
                p = dq2(lo[0], lo[1], shf[bn], s2[bn], c2[bn]); bfr[0]=p[0]; bfr[1]=p[1];
                p = dq2(lo[2], lo[3], shf[bn], s2[bn], c2[bn]); bfr[2]=p[0]; bfr[3]=p[1];
                p = dq2(hi[0], hi[1], shf[bn], s2[bn], c2[bn]); bfr[4]=p[0]; bfr[5]=p[1];
                p = dq2(hi[2], hi[3], shf[bn], s2[bn], c2[bn]); bfr[6]=p[0]; bfr[7]=p[1];
                #pragma unroll
                for (int am = 0; am < 8; ++am)
                    acc[am][bn] = __builtin_amdgcn_mfma_f32_16x16x32_f16(
                        af[am], bfr, acc[am][bn], 0, 0, 0);
            }
        }
    }
    #pragma unroll
    for (int bn = 0; bn < 4; ++bn) {
        const int col = bn0 + wn0 + bn * 16 + (lane & 15);
        const float b_f = bias[col];
        #pragma unroll
        for (int am = 0; am < 8; ++am) {
            const int row_base = bm0 + am * 16 + ((lane >> 4) << 2);
            #pragma unroll
            for (int r = 0; r < 4; ++r) {
                const int row = row_base + r;
                if (row < M)
                    out[(size_t)row * N_DIM + col] = acc[am][bn][r] + b_f;
            }
        }
    }
#undef LOAD_TILE
}

extern "C" void kernel_launch(void* const* d_in, const int* in_sizes, int n_in,
                              void* d_out, int out_size, void* d_ws, size_t ws_size,
                              hipStream_t stream) {
    const float* x    = (const float*)d_in[0];
    const int*   qw   = (const int*)d_in[1];
    const int*   qz   = (const int*)d_in[2];
    const float* sc   = (const float*)d_in[3];
    const float* bias = (const float*)d_in[4];
    float*       out  = (float*)d_out;

    const int M = in_sizes[0] / K_DIM;
    const int mtiles = (M + BM - 1) / BM;

    const size_t x_bytes = (size_t)M * K_DIM * 2;
    const size_t w_bytes = (size_t)N_DIM * K_DIM * 2;

    if (ws_size >= x_bytes + w_bytes) {
        ushort*   xf  = (ushort*)d_ws;
        _Float16* W16 = (_Float16*)((char*)d_ws + x_bytes);
        cvt_x_kernel<<<dim3(2048), dim3(256), 0, stream>>>(x, xf, (M * K_DIM) / 8);
        dequant_w_kernel<<<dim3(WORDS_N / 8, K_DIM / 64), dim3(256), 0, stream>>>(qw, qz, sc, W16);
        const int nwg = (N_DIM / BN) * mtiles;
        awq_gemm_split<<<dim3(nwg), dim3(256), 0, stream>>>(
            xf, W16, bias, out, M, mtiles, nwg);
    } else if (ws_size >= x_bytes) {
        ushort* xf = (ushort*)d_ws;
        cvt_x_kernel<<<dim3(2048), dim3(256), 0, stream>>>(x, xf, (M * K_DIM) / 8);
        awq_gemm_fused<true><<<dim3(N_DIM / BN, mtiles), dim3(256), 0, stream>>>(
            xf, qw, qz, sc, bias, out, M);
    } else {
        awq_gemm_fused<false><<<dim3(N_DIM / BN, mtiles), dim3(256), 0, stream>>>(
            x, qw, qz, sc, bias, out, M);
    }
}

// Round 10
// 269.411 us; speedup vs baseline: 1.2981x; 1.2981x over previous
//
#include <hip/hip_runtime.h>
#include <stdint.h>

#define K_DIM 4096
#define N_DIM 11008
#define WORDS_N 1376          // N_DIM / 8 packed words
#define BM 128
#define BN 256
#define BK 64
#define ASTR 72               // fused-fallback As stride
#define WSTR 68               // fused-fallback Wq stride (ints)

typedef _Float16 f16x2 __attribute__((ext_vector_type(2)));
typedef _Float16 f16x8 __attribute__((ext_vector_type(8)));
typedef float    f32x4 __attribute__((ext_vector_type(4)));
typedef float    f32x8 __attribute__((ext_vector_type(8)));
typedef int      int4v __attribute__((ext_vector_type(4)));
typedef int      int2v __attribute__((ext_vector_type(2)));
typedef unsigned short ushort;
typedef unsigned int u32;

__device__ __forceinline__ f16x2 dq2(int wa, int wb, int shf, f16x2 s2, f16x2 c2) {
    u32 t0 = ((u32)wa >> shf) & 0xFu;
    u32 t1 = ((u32)wb >> shf) & 0xFu;
    u32 h  = 0x64006400u | t0 | (t1 << 16);
    f16x2 q = __builtin_bit_cast(f16x2, h);
    q = q - (f16x2)((_Float16)1024.0f);
    return q * s2 + c2;
}

__device__ __forceinline__ void gload16(const void* g, void* l) {
    __builtin_amdgcn_global_load_lds(
        (const __attribute__((address_space(1))) unsigned int*)g,
        (__attribute__((address_space(3))) unsigned int*)l, 16, 0, 0);
}

// ---- pre-pass 1: x f32 -> fp16 ----
__global__ __launch_bounds__(256)
void cvt_x_kernel(const float* __restrict__ x, ushort* __restrict__ xf, int n8) {
    for (int i = blockIdx.x * 256 + threadIdx.x; i < n8; i += gridDim.x * 256) {
        f32x4 a = *(const f32x4*)(x + (size_t)i * 8);
        f32x4 b = *(const f32x4*)(x + (size_t)i * 8 + 4);
        int4v o;
        o[0] = __builtin_bit_cast(int, __builtin_amdgcn_cvt_pkrtz(a[0], a[1]));
        o[1] = __builtin_bit_cast(int, __builtin_amdgcn_cvt_pkrtz(a[2], a[3]));
        o[2] = __builtin_bit_cast(int, __builtin_amdgcn_cvt_pkrtz(b[0], b[1]));
        o[3] = __builtin_bit_cast(int, __builtin_amdgcn_cvt_pkrtz(b[2], b[3]));
        *(int4v*)(xf + (size_t)i * 8) = o;
    }
}

// ---- pre-pass 2: dequant qweight -> W16[n][k] fp16 row-major (proven round 9) ----
__global__ __launch_bounds__(256)
void dequant_w_kernel(const int* __restrict__ qw,
                      const int* __restrict__ qz,
                      const float* __restrict__ sc,
                      _Float16* __restrict__ W16)
{
    __shared__ __align__(16) int Wq[8 * WSTR];
    const int t  = threadIdx.x;
    const int w0 = blockIdx.x * 8;
    const int n0 = blockIdx.x * 64;
    const int k0 = blockIdx.y * 64;
    {
        const int k  = t >> 2;
        const int wp = (t & 3) * 2;
        const int2v v = *(const int2v*)(qw + (size_t)(k0 + k) * WORDS_N + w0 + wp);
        Wq[(wp + 0) * WSTR + k] = v[0];
        Wq[(wp + 1) * WSTR + k] = v[1];
    }
    __syncthreads();

    const int n   = t & 63;
    const int oc0 = t >> 6;
    const int w   = n >> 3;
    const int j   = n & 7;
    const int shf = ((j & 1) << 4) + ((j >> 1) << 2);
    const int g   = k0 >> 7;

    const float s  = sc[(size_t)g * N_DIM + n0 + n];
    const int   zq = (qz[(size_t)g * WORDS_N + w0 + w] >> shf) & 0xF;
    const float nz = -(float)zq * s;

    #pragma unroll
    for (int oo = 0; oo < 2; ++oo) {
        const int oc = oc0 + oo * 4;
        const int4v lo = *(const int4v*)&Wq[w * WSTR + oc * 8];
        const int4v hi = *(const int4v*)&Wq[w * WSTR + oc * 8 + 4];
        f16x8 h;
        #pragma unroll
        for (int r = 0; r < 4; ++r)
            h[r] = (_Float16)((float)((lo[r] >> shf) & 0xF) * s + nz);
        #pragma unroll
        for (int r = 0; r < 4; ++r)
            h[4 + r] = (_Float16)((float)((hi[r] >> shf) & 0xF) * s + nz);
        *(f16x8*)(W16 + (size_t)(n0 + n) * K_DIM + k0 + oc * 8) = h;
    }
}

// ---- main GEMM: counted-vmcnt dbuf pipeline, gload_lds + T2 swizzle ----
// 128x128 tile, BK=64, 256 thr (4 waves, 2x2, each 64x64 out).
__global__ __launch_bounds__(256, 2)
void awq_gemm_pipe(const ushort* __restrict__ x16,
                   const _Float16* __restrict__ W16,
                   const float* __restrict__ bias,
                   float* __restrict__ out,
                   int M, int nwg)
{
    __shared__ __align__(16) _Float16 As[2][128 * 64];  // 2 x 16 KB
    __shared__ __align__(16) _Float16 Bs[2][128 * 64];  // 2 x 16 KB  (64 KB total)

    const int tid  = threadIdx.x;
    const int lane = tid & 63;
    const int wid  = tid >> 6;

    // XCD swizzle: nwg = 86*16 divisible by 8 -> simple bijection; consecutive
    // logical g share bx (B panel) on one XCD's L2.
    const int hh  = blockIdx.x;
    const int g   = (hh & 7) * (nwg >> 3) + (hh >> 3);
    const int bx  = g >> 4;          // 0..85  N tile
    const int by  = g & 15;          // 0..15  M tile
    const int bn0 = bx * 128;
    const int bm0 = by * 128;

    const int wm0 = (wid >> 1) * 64;
    const int wn0 = (wid & 1) * 64;

    // ---- staging constants: wave w stages rows w*32..+32 of each tile ----
    // LDS linear [row][64]; global source slot pre-swizzled: slot = (lane&7)^(lane>>3)
    const int srow = lane >> 3;                 // 0..7 within 8-row chunk
    const int slot = (lane & 7) ^ srow;         // inverse-swizzled 16B slot
    const ushort*   aSrc = x16 + (size_t)(bm0 + wid * 32 + srow) * K_DIM + slot * 8;
    const _Float16* bSrc = W16 + (size_t)(bn0 + wid * 32 + srow) * K_DIM + slot * 8;

#define STAGE(BUF, K0)                                                          \
    {                                                                           \
        _Pragma("unroll")                                                       \
        for (int j = 0; j < 4; ++j)                                             \
            gload16(aSrc + (size_t)(K0) + j * 8 * K_DIM,                        \
                    &As[BUF][(wid * 32 + j * 8) * 64]);                         \
        _Pragma("unroll")                                                       \
        for (int j = 0; j < 4; ++j)                                             \
            gload16(bSrc + (size_t)(K0) + j * 8 * K_DIM,                        \
                    &Bs[BUF][(wid * 32 + j * 8) * 64]);                         \
    }

    f32x4 acc[4][4];
    #pragma unroll
    for (int i = 0; i < 4; ++i)
        #pragma unroll
        for (int j = 0; j < 4; ++j)
            acc[i][j] = (f32x4){0.f, 0.f, 0.f, 0.f};

    STAGE(0, 0);
    STAGE(1, 64);

    const int rd_sw = (lane & 7) << 4;   // read-side XOR (= (row&7)<<4)
    const int rrow  = lane & 15;

    const int NT = K_DIM / 64;  // 64
    for (int t = 0; t < NT; ++t) {
        if (t < NT - 1) { asm volatile("s_waitcnt vmcnt(8)" ::: "memory"); }
        else            { asm volatile("s_waitcnt vmcnt(0)" ::: "memory"); }
        __builtin_amdgcn_sched_barrier(0);
        __builtin_amdgcn_s_barrier();        // tile t visible in buf[t&1]
        __builtin_amdgcn_sched_barrier(0);

        const int cur = t & 1;
        const char* aB = (const char*)&As[cur][0];
        const char* bB = (const char*)&Bs[cur][0];

        #pragma unroll
        for (int ks = 0; ks < 2; ++ks) {
            const int kb = ks * 64 + ((lane >> 4) << 4);   // octet byte offset
            f16x8 af[4], bf[4];
            #pragma unroll
            for (int m = 0; m < 4; ++m)
                af[m] = *(const f16x8*)(aB + (wm0 + m * 16 + rrow) * 128 + (kb ^ rd_sw));
            #pragma unroll
            for (int n = 0; n < 4; ++n)
                bf[n] = *(const f16x8*)(bB + (wn0 + n * 16 + rrow) * 128 + (kb ^ rd_sw));

            __builtin_amdgcn_s_setprio(1);
            #pragma unroll
            for (int m = 0; m < 4; ++m)
                #pragma unroll
                for (int n = 0; n < 4; ++n)
                    acc[m][n] = __builtin_amdgcn_mfma_f32_16x16x32_f16(
                        af[m], bf[n], acc[m][n], 0, 0, 0);
            __builtin_amdgcn_s_setprio(0);
        }

        __builtin_amdgcn_sched_barrier(0);
        __builtin_amdgcn_s_barrier();        // all waves done reading buf[cur]
        __builtin_amdgcn_sched_barrier(0);

        if (t < NT - 2) STAGE(cur, (t + 2) * 64);   // refill freed buffer; stays in flight
    }
#undef STAGE

    // epilogue: C/D col=lane&15, row=(lane>>4)*4+r (m89-verified)
    #pragma unroll
    for (int n = 0; n < 4; ++n) {
        const int col = bn0 + wn0 + n * 16 + (lane & 15);
        const float b_f = bias[col];
        #pragma unroll
        for (int m = 0; m < 4; ++m) {
            const int row_base = bm0 + wm0 + m * 16 + ((lane >> 4) << 2);
            #pragma unroll
            for (int r = 0; r < 4; ++r) {
                const int row = row_base + r;
                if (row < M)
                    out[(size_t)row * N_DIM + col] = acc[m][n][r] + b_f;
            }
        }
    }
}

// ---- fallback: fused kernel (proven rounds 6-8) ----
template <bool XF16>
__global__ __launch_bounds__(256, 2)
void awq_gemm_fused(const void* __restrict__ xin,
                    const int* __restrict__ qw,
                    const int* __restrict__ qz,
                    const float* __restrict__ sc,
                    const float* __restrict__ bias,
                    float* __restrict__ out,
                    int M)
{
    __shared__ __align__(16) _Float16 Asf[BM * ASTR];
    __shared__ __align__(16) int Wq[32 * WSTR];

    const int tid  = threadIdx.x;
    const int lane = tid & 63;
    const int wid  = tid >> 6;
    const int bn0 = blockIdx.x * BN;
    const int bm0 = blockIdx.y * BM;
    const int w0  = bn0 >> 3;
    const int wn0 = wid * 64;
    const int a_row = tid >> 3;
    const int a_col = (tid & 7) * 8;
    const int b_krow = tid >> 2;
    const int b_wg   = (tid & 3) * 4;

    int n_loc[4], w_loc[4], shf[4];
    #pragma unroll
    for (int bn = 0; bn < 4; ++bn) {
        n_loc[bn] = wn0 + bn * 16 + (lane & 15);
        w_loc[bn] = n_loc[bn] >> 3;
        int j = n_loc[bn] & 7;
        shf[bn] = ((j & 1) << 4) + ((j >> 1) << 2);
    }
    f16x2 s2[4], c2[4];
    f32x4 acc[8][4];
    #pragma unroll
    for (int i = 0; i < 8; ++i)
        #pragma unroll
        for (int j = 0; j < 4; ++j)
            acc[i][j] = (f32x4){0.f, 0.f, 0.f, 0.f};
    int4v aReg16[4];
    f32x8 aReg32[4];
    int4v bReg[2];
    const ushort* x16 = (const ushort*)xin;
    const float*  x32 = (const float*)xin;

#define LOAD_TILE(K0)                                                                  \
    {                                                                                  \
        _Pragma("unroll")                                                              \
        for (int i = 0; i < 4; ++i) {                                                  \
            int row = bm0 + a_row + i * 32;                                            \
            if constexpr (XF16) {                                                      \
                if (row < M)                                                           \
                    aReg16[i] = *(const int4v*)(x16 + (size_t)row * K_DIM + (K0) + a_col); \
                else aReg16[i] = (int4v){0, 0, 0, 0};                                  \
            } else {                                                                   \
                if (row < M)                                                           \
                    aReg32[i] = *(const f32x8*)(x32 + (size_t)row * K_DIM + (K0) + a_col); \
                else aReg32[i] = (f32x8){0.f,0.f,0.f,0.f,0.f,0.f,0.f,0.f};             \
            }                                                                          \
        }                                                                              \
        bReg[0] = *(const int4v*)(qw + (size_t)((K0) + b_krow) * WORDS_N + w0 + b_wg);      \
        bReg[1] = *(const int4v*)(qw + (size_t)((K0) + b_krow) * WORDS_N + w0 + b_wg + 16); \
    }

    LOAD_TILE(0);
    const int NT = K_DIM / BK;
    for (int t = 0; t < NT; ++t) {
        const int k0 = t * BK;
        __syncthreads();
        #pragma unroll
        for (int i = 0; i < 4; ++i) {
            if constexpr (XF16) {
                *(int4v*)&Asf[(a_row + i * 32) * ASTR + a_col] = aReg16[i];
            } else {
                f16x8 hh2;
                #pragma unroll
                for (int r = 0; r < 4; ++r) {
                    f16x2 p = __builtin_bit_cast(f16x2,
                        __builtin_amdgcn_cvt_pkrtz(aReg32[i][2*r], aReg32[i][2*r+1]));
                    hh2[2*r] = p[0]; hh2[2*r+1] = p[1];
                }
                *(f16x8*)&Asf[(a_row + i * 32) * ASTR + a_col] = hh2;
            }
        }
        #pragma unroll
        for (int c = 0; c < 4; ++c) {
            Wq[(b_wg + c) * WSTR + b_krow]      = bReg[0][c];
            Wq[(b_wg + 16 + c) * WSTR + b_krow] = bReg[1][c];
        }
        __syncthreads();
        if (t + 1 < NT) LOAD_TILE(k0 + BK);
        if ((t & 1) == 0) {
            const int gg = k0 >> 7;
            #pragma unroll
            for (int bn = 0; bn < 4; ++bn) {
                float s = sc[(size_t)gg * N_DIM + bn0 + n_loc[bn]];
                int zq  = (qz[(size_t)gg * WORDS_N + w0 + w_loc[bn]] >> shf[bn]) & 0xF;
                _Float16 sh = (_Float16)s;
                _Float16 nz = (_Float16)(-(float)zq * s);
                s2[bn] = (f16x2){sh, sh};
                c2[bn] = (f16x2){nz, nz};
            }
        }
        #pragma unroll
        for (int ks = 0; ks < 2; ++ks) {
            const int kk = ks * 32 + (lane >> 4) * 8;
            f16x8 af[8];
            #pragma unroll
            for (int am = 0; am < 8; ++am)
                af[am] = *(const f16x8*)&Asf[(am * 16 + (lane & 15)) * ASTR + kk];
            #pragma unroll
            for (int bn = 0; bn < 4; ++bn) {
                const int4v lo = *(const int4v*)&Wq[w_loc[bn] * WSTR + kk];
                const int4v hi = *(const int4v*)&Wq[w_loc[bn] * WSTR + kk + 4];
                f16x8 bfr;
                f16x2 p;
                p = dq2(lo[0], lo[1], shf[bn], s2[bn], c2[bn]); bfr[0]=p[0]; bfr[1]=p[1];
                p = dq2(lo[2], lo[3], shf[bn], s2[bn], c2[bn]); bfr[2]=p[0]; bfr[3]=p[1];
                p = dq2(hi[0], hi[1], shf[bn], s2[bn], c2[bn]); bfr[4]=p[0]; bfr[5]=p[1];
                p = dq2(hi[2], hi[3], shf[bn], s2[bn], c2[bn]); bfr[6]=p[0]; bfr[7]=p[1];
                #pragma unroll
                for (int am = 0; am < 8; ++am)
                    acc[am][bn] = __builtin_amdgcn_mfma_f32_16x16x32_f16(
                        af[am], bfr, acc[am][bn], 0, 0, 0);
            }
        }
    }
    #pragma unroll
    for (int bn = 0; bn < 4; ++bn) {
        const int col = bn0 + wn0 + bn * 16 + (lane & 15);
        const float b_f = bias[col];
        #pragma unroll
        for (int am = 0; am < 8; ++am) {
            const int row_base = bm0 + am * 16 + ((lane >> 4) << 2);
            #pragma unroll
            for (int r = 0; r < 4; ++r) {
                const int row = row_base + r;
                if (row < M)
                    out[(size_t)row * N_DIM + col] = acc[am][bn][r] + b_f;
            }
        }
    }
#undef LOAD_TILE
}

extern "C" void kernel_launch(void* const* d_in, const int* in_sizes, int n_in,
                              void* d_out, int out_size, void* d_ws, size_t ws_size,
                              hipStream_t stream) {
    const float* x    = (const float*)d_in[0];
    const int*   qw   = (const int*)d_in[1];
    const int*   qz   = (const int*)d_in[2];
    const float* sc   = (const float*)d_in[3];
    const float* bias = (const float*)d_in[4];
    float*       out  = (float*)d_out;

    const int M = in_sizes[0] / K_DIM;
    const size_t x_bytes = (size_t)M * K_DIM * 2;
    const size_t w_bytes = (size_t)N_DIM * K_DIM * 2;

    if (ws_size >= x_bytes + w_bytes && (M % 128) == 0) {
        ushort*   xf  = (ushort*)d_ws;
        _Float16* W16 = (_Float16*)((char*)d_ws + x_bytes);
        cvt_x_kernel<<<dim3(2048), dim3(256), 0, stream>>>(x, xf, (M * K_DIM) / 8);
        dequant_w_kernel<<<dim3(WORDS_N / 8, K_DIM / 64), dim3(256), 0, stream>>>(qw, qz, sc, W16);
        const int nwg = (N_DIM / 128) * (M / 128);   // 86 x 16 = 1376, %8==0
        awq_gemm_pipe<<<dim3(nwg), dim3(256), 0, stream>>>(xf, W16, bias, out, M, nwg);
    } else if (ws_size >= x_bytes) {
        ushort* xf = (ushort*)d_ws;
        const int mtiles = (M + BM - 1) / BM;
        cvt_x_kernel<<<dim3(2048), dim3(256), 0, stream>>>(x, xf, (M * K_DIM) / 8);
        awq_gemm_fused<true><<<dim3(N_DIM / BN, mtiles), dim3(256), 0, stream>>>(
            xf, qw, qz, sc, bias, out, M);
    } else {
        const int mtiles = (M + BM - 1) / BM;
        awq_gemm_fused<false><<<dim3(N_DIM / BN, mtiles), dim3(256), 0, stream>>>(
            x, qw, qz, sc, bias, out, M);
    }
}

// Round 11
// 258.840 us; speedup vs baseline: 1.3511x; 1.0408x over previous
//
#include <hip/hip_runtime.h>
#include <stdint.h>

#define K_DIM 4096
#define N_DIM 11008
#define WORDS_N 1376          // N_DIM / 8 packed words
#define BM 128
#define BN 256
#define BK 64
#define ASTR 72               // fused-fallback As stride
#define WSTR 68               // fused-fallback Wq stride (ints)

typedef _Float16 f16x2 __attribute__((ext_vector_type(2)));
typedef _Float16 f16x8 __attribute__((ext_vector_type(8)));
typedef float    f32x4 __attribute__((ext_vector_type(4)));
typedef float    f32x8 __attribute__((ext_vector_type(8)));
typedef int      int4v __attribute__((ext_vector_type(4)));
typedef int      int2v __attribute__((ext_vector_type(2)));
typedef unsigned short ushort;
typedef unsigned int u32;

__device__ __forceinline__ f16x2 dq2(int wa, int wb, int shf, f16x2 s2, f16x2 c2) {
    u32 t0 = ((u32)wa >> shf) & 0xFu;
    u32 t1 = ((u32)wb >> shf) & 0xFu;
    u32 h  = 0x64006400u | t0 | (t1 << 16);
    f16x2 q = __builtin_bit_cast(f16x2, h);
    q = q - (f16x2)((_Float16)1024.0f);
    return q * s2 + c2;
}

__device__ __forceinline__ void gload16(const void* g, void* l) {
    __builtin_amdgcn_global_load_lds(
        (const __attribute__((address_space(1))) unsigned int*)g,
        (__attribute__((address_space(3))) unsigned int*)l, 16, 0, 0);
}

// ---- pre-pass 1: x f32 -> fp16 ----
__global__ __launch_bounds__(256)
void cvt_x_kernel(const float* __restrict__ x, ushort* __restrict__ xf, int n8) {
    for (int i = blockIdx.x * 256 + threadIdx.x; i < n8; i += gridDim.x * 256) {
        f32x4 a = *(const f32x4*)(x + (size_t)i * 8);
        f32x4 b = *(const f32x4*)(x + (size_t)i * 8 + 4);
        int4v o;
        o[0] = __builtin_bit_cast(int, __builtin_amdgcn_cvt_pkrtz(a[0], a[1]));
        o[1] = __builtin_bit_cast(int, __builtin_amdgcn_cvt_pkrtz(a[2], a[3]));
        o[2] = __builtin_bit_cast(int, __builtin_amdgcn_cvt_pkrtz(b[0], b[1]));
        o[3] = __builtin_bit_cast(int, __builtin_amdgcn_cvt_pkrtz(b[2], b[3]));
        *(int4v*)(xf + (size_t)i * 8) = o;
    }
}

// ---- pre-pass 2: dequant qweight -> W in MFMA-fragment order ----
// unit = f16x8. layout: unit_idx = (ntile*512 + kidx)*16 + (col&15)
//   ntile = col>>4, kidx = k>>3  (512 = K_DIM/8)
// A wave's B-fragment load (16x16x32, k-octet per lane>>4) is then
// 64 consecutive units = one coalesced 1KB read.
__global__ __launch_bounds__(256)
void dequant_w_kernel(const int* __restrict__ qw,
                      const int* __restrict__ qz,
                      const float* __restrict__ sc,
                      f16x8* __restrict__ Wf)
{
    __shared__ __align__(16) int Wq[8 * WSTR];
    const int t  = threadIdx.x;
    const int w0 = blockIdx.x * 8;
    const int n0 = blockIdx.x * 64;
    const int k0 = blockIdx.y * 64;
    {
        const int k  = t >> 2;
        const int wp = (t & 3) * 2;
        const int2v v = *(const int2v*)(qw + (size_t)(k0 + k) * WORDS_N + w0 + wp);
        Wq[(wp + 0) * WSTR + k] = v[0];
        Wq[(wp + 1) * WSTR + k] = v[1];
    }
    __syncthreads();

    const int n   = t & 63;
    const int oc0 = t >> 6;
    const int w   = n >> 3;
    const int j   = n & 7;
    const int shf = ((j & 1) << 4) + ((j >> 1) << 2);
    const int g   = k0 >> 7;

    const int   nn = n0 + n;
    const float s  = sc[(size_t)g * N_DIM + nn];
    const int   zq = (qz[(size_t)g * WORDS_N + w0 + w] >> shf) & 0xF;
    const float nz = -(float)zq * s;

    #pragma unroll
    for (int oo = 0; oo < 2; ++oo) {
        const int oc = oc0 + oo * 4;
        const int4v lo = *(const int4v*)&Wq[w * WSTR + oc * 8];
        const int4v hi = *(const int4v*)&Wq[w * WSTR + oc * 8 + 4];
        f16x8 h;
        #pragma unroll
        for (int r = 0; r < 4; ++r)
            h[r] = (_Float16)((float)((lo[r] >> shf) & 0xF) * s + nz);
        #pragma unroll
        for (int r = 0; r < 4; ++r)
            h[4 + r] = (_Float16)((float)((hi[r] >> shf) & 0xF) * s + nz);
        const size_t kidx = (size_t)((k0 >> 3) + oc);
        Wf[((size_t)(nn >> 4) * 512 + kidx) * 16 + (nn & 15)] = h;
    }
}

// ---- main GEMM: A via gload_lds+swizzle pipeline, B double-buffered in regs
//      from fragment-ordered Wf (coalesced 1KB L2 reads) ----
__global__ __launch_bounds__(256, 2)
void awq_gemm_pipe(const ushort* __restrict__ x16,
                   const f16x8* __restrict__ Wf,
                   const float* __restrict__ bias,
                   float* __restrict__ out,
                   int M, int nwg)
{
    __shared__ __align__(16) _Float16 As[2][128 * 64];  // 2 x 16 KB, A only

    const int tid  = threadIdx.x;
    const int lane = tid & 63;
    const int wid  = tid >> 6;

    // XCD swizzle: nwg divisible by 8; consecutive logical g share bx (B panel).
    const int hh  = blockIdx.x;
    const int g   = (hh & 7) * (nwg >> 3) + (hh >> 3);
    const int bx  = g >> 4;          // N tile
    const int by  = g & 15;          // M tile
    const int bn0 = bx * 128;
    const int bm0 = by * 128;

    const int wm0 = (wid >> 1) * 64;
    const int wn0 = (wid & 1) * 64;

    // A staging (proven round 10): linear LDS dest, pre-swizzled global slot
    const int srow = lane >> 3;
    const int slot = (lane & 7) ^ srow;
    const ushort* aSrc = x16 + (size_t)(bm0 + wid * 32 + srow) * K_DIM + slot * 8;

#define STAGE_A(BUF, K0)                                                        \
    {                                                                           \
        _Pragma("unroll")                                                       \
        for (int jj = 0; jj < 4; ++jj)                                          \
            gload16(aSrc + (size_t)(K0) + jj * 8 * K_DIM,                       \
                    &As[BUF][(wid * 32 + jj * 8) * 64]);                        \
    }

    // B fragment bases: ntile = (bn0+wn0)/16 + n ; unit idx = ntile*8192 + K0*2 + ks*64 + lane
    size_t nb[4];
    #pragma unroll
    for (int n = 0; n < 4; ++n)
        nb[n] = ((size_t)((bn0 + wn0) >> 4) + n) * 8192 + lane;

    f32x4 acc[4][4];
    #pragma unroll
    for (int i = 0; i < 4; ++i)
        #pragma unroll
        for (int j = 0; j < 4; ++j)
            acc[i][j] = (f32x4){0.f, 0.f, 0.f, 0.f};

    f16x8 BR0[8], BR1[8];
    const int NT = K_DIM / 64;  // 64

#define LOADB(DST, T)                                                           \
    {                                                                           \
        const size_t koff = (size_t)(T) * 128;                                  \
        _Pragma("unroll")                                                       \
        for (int jj = 0; jj < 8; ++jj)                                          \
            DST[jj] = Wf[nb[jj & 3] + koff + (size_t)(jj >> 2) * 64];           \
    }

    const int rd_sw = (lane & 7) << 4;
    const int rrow  = lane & 15;

    // prologue: A[0], B[0], A[1] (issue order matters for vmcnt counting)
    STAGE_A(0, 0);
    LOADB(BR0, 0);
    STAGE_A(1, 64);

#define ITER(T, BRD, BWR)                                                          \
    {                                                                              \
        asm volatile("s_waitcnt vmcnt(12)" ::: "memory");                          \
        __builtin_amdgcn_sched_barrier(0);                                         \
        __builtin_amdgcn_s_barrier();                                              \
        __builtin_amdgcn_sched_barrier(0);                                         \
        { const int tn = ((T) + 1 < NT) ? (T) + 1 : NT - 1; LOADB(BWR, tn); }      \
        __builtin_amdgcn_sched_barrier(0);                                         \
        const char* aB = (const char*)&As[(T) & 1][0];                             \
        _Pragma("unroll")                                                          \
        for (int ks = 0; ks < 2; ++ks) {                                           \
            const int kb = ks * 64 + ((lane >> 4) << 4);                           \
            f16x8 af[4];                                                           \
            _Pragma("unroll")                                                      \
            for (int m = 0; m < 4; ++m)                                            \
                af[m] = *(const f16x8*)(aB + (wm0 + m * 16 + rrow) * 128 + (kb ^ rd_sw)); \
            __builtin_amdgcn_s_setprio(1);                                         \
            _Pragma("unroll")                                                      \
            for (int m = 0; m < 4; ++m)                                            \
                _Pragma("unroll")                                                  \
                for (int n = 0; n < 4; ++n)                                        \
                    acc[m][n] = __builtin_amdgcn_mfma_f32_16x16x32_f16(            \
                        af[m], BRD[ks * 4 + n], acc[m][n], 0, 0, 0);               \
            __builtin_amdgcn_s_setprio(0);                                         \
        }                                                                          \
        __builtin_amdgcn_sched_barrier(0);                                         \
        __builtin_amdgcn_s_barrier();                                              \
        __builtin_amdgcn_sched_barrier(0);                                         \
        { const int t2 = ((T) + 2 < NT) ? (T) + 2 : NT - 1; STAGE_A((T) & 1, t2 * 64); } \
    }

    for (int t = 0; t < NT; t += 2) {
        ITER(t,     BR0, BR1);
        ITER(t + 1, BR1, BR0);
    }
#undef ITER
#undef LOADB
#undef STAGE_A

    // epilogue: C/D col=lane&15, row=(lane>>4)*4+r (m89-verified)
    #pragma unroll
    for (int n = 0; n < 4; ++n) {
        const int col = bn0 + wn0 + n * 16 + (lane & 15);
        const float b_f = bias[col];
        #pragma unroll
        for (int m = 0; m < 4; ++m) {
            const int row_base = bm0 + wm0 + m * 16 + ((lane >> 4) << 2);
            #pragma unroll
            for (int r = 0; r < 4; ++r) {
                const int row = row_base + r;
                if (row < M)
                    out[(size_t)row * N_DIM + col] = acc[m][n][r] + b_f;
            }
        }
    }
}

// ---- fallback: fused kernel (proven rounds 6-8) ----
template <bool XF16>
__global__ __launch_bounds__(256, 2)
void awq_gemm_fused(const void* __restrict__ xin,
                    const int* __restrict__ qw,
                    const int* __restrict__ qz,
                    const float* __restrict__ sc,
                    const float* __restrict__ bias,
                    float* __restrict__ out,
                    int M)
{
    __shared__ __align__(16) _Float16 Asf[BM * ASTR];
    __shared__ __align__(16) int Wq[32 * WSTR];

    const int tid  = threadIdx.x;
    const int lane = tid & 63;
    const int wid  = tid >> 6;
    const int bn0 = blockIdx.x * BN;
    const int bm0 = blockIdx.y * BM;
    const int w0  = bn0 >> 3;
    const int wn0 = wid * 64;
    const int a_row = tid >> 3;
    const int a_col = (tid & 7) * 8;
    const int b_krow = tid >> 2;
    const int b_wg   = (tid & 3) * 4;

    int n_loc[4], w_loc[4], shf[4];
    #pragma unroll
    for (int bn = 0; bn < 4; ++bn) {
        n_loc[bn] = wn0 + bn * 16 + (lane & 15);
        w_loc[bn] = n_loc[bn] >> 3;
        int j = n_loc[bn] & 7;
        shf[bn] = ((j & 1) << 4) + ((j >> 1) << 2);
    }
    f16x2 s2[4], c2[4];
    f32x4 acc[8][4];
    #pragma unroll
    for (int i = 0; i < 8; ++i)
        #pragma unroll
        for (int j = 0; j < 4; ++j)
            acc[i][j] = (f32x4){0.f, 0.f, 0.f, 0.f};
    int4v aReg16[4];
    f32x8 aReg32[4];
    int4v bReg[2];
    const ushort* x16 = (const ushort*)xin;
    const float*  x32 = (const float*)xin;

#define LOAD_TILE(K0)                                                                  \
    {                                                                                  \
        _Pragma("unroll")                                                              \
        for (int i = 0; i < 4; ++i) {                                                  \
            int row = bm0 + a_row + i * 32;                                            \
            if constexpr (XF16) {                                                      \
                if (row < M)                                                           \
                    aReg16[i] = *(const int4v*)(x16 + (size_t)row * K_DIM + (K0) + a_col); \
                else aReg16[i] = (int4v){0, 0, 0, 0};                                  \
            } else {                                                                   \
                if (row < M)                                                           \
                    aReg32[i] = *(const f32x8*)(x32 + (size_t)row * K_DIM + (K0) + a_col); \
                else aReg32[i] = (f32x8){0.f,0.f,0.f,0.f,0.f,0.f,0.f,0.f};             \
            }                                                                          \
        }                                                                              \
        bReg[0] = *(const int4v*)(qw + (size_t)((K0) + b_krow) * WORDS_N + w0 + b_wg);      \
        bReg[1] = *(const int4v*)(qw + (size_t)((K0) + b_krow) * WORDS_N + w0 + b_wg + 16); \
    }

    LOAD_TILE(0);
    const int NT = K_DIM / BK;
    for (int t = 0; t < NT; ++t) {
        const int k0 = t * BK;
        __syncthreads();
        #pragma unroll
        for (int i = 0; i < 4; ++i) {
            if constexpr (XF16) {
                *(int4v*)&Asf[(a_row + i * 32) * ASTR + a_col] = aReg16[i];
            } else {
                f16x8 hh2;
                #pragma unroll
                for (int r = 0; r < 4; ++r) {
                    f16x2 p = __builtin_bit_cast(f16x2,
                        __builtin_amdgcn_cvt_pkrtz(aReg32[i][2*r], aReg32[i][2*r+1]));
                    hh2[2*r] = p[0]; hh2[2*r+1] = p[1];
                }
                *(f16x8*)&Asf[(a_row + i * 32) * ASTR + a_col] = hh2;
            }
        }
        #pragma unroll
        for (int c = 0; c < 4; ++c) {
            Wq[(b_wg + c) * WSTR + b_krow]      = bReg[0][c];
            Wq[(b_wg + 16 + c) * WSTR + b_krow] = bReg[1][c];
        }
        __syncthreads();
        if (t + 1 < NT) LOAD_TILE(k0 + BK);
        if ((t & 1) == 0) {
            const int gg = k0 >> 7;
            #pragma unroll
            for (int bn = 0; bn < 4; ++bn) {
                float s = sc[(size_t)gg * N_DIM + bn0 + n_loc[bn]];
                int zq  = (qz[(size_t)gg * WORDS_N + w0 + w_loc[bn]] >> shf[bn]) & 0xF;
                _Float16 sh = (_Float16)s;
                _Float16 nz = (_Float16)(-(float)zq * s);
                s2[bn] = (f16x2){sh, sh};
                c2[bn] = (f16x2){nz, nz};
            }
        }
        #pragma unroll
        for (int ks = 0; ks < 2; ++ks) {
            const int kk = ks * 32 + (lane >> 4) * 8;
            f16x8 af[8];
            #pragma unroll
            for (int am = 0; am < 8; ++am)
                af[am] = *(const f16x8*)&Asf[(am * 16 + (lane & 15)) * ASTR + kk];
            #pragma unroll
            for (int bn = 0; bn < 4; ++bn) {
                const int4v lo = *(const int4v*)&Wq[w_loc[bn] * WSTR + kk];
                const int4v hi = *(const int4v*)&Wq[w_loc[bn] * WSTR + kk + 4];
                f16x8 bfr;
                f16x2 p;
                p = dq2(lo[0], lo[1], shf[bn], s2[bn], c2[bn]); bfr[0]=p[0]; bfr[1]=p[1];
                p = dq2(lo[2], lo[3], shf[bn], s2[bn], c2[bn]); bfr[2]=p[0]; bfr[3]=p[1];
                p = dq2(hi[0], hi[1], shf[bn], s2[bn], c2[bn]); bfr[4]=p[0]; bfr[5]=p[1];
                p = dq2(hi[2], hi[3], shf[bn], s2[bn], c2[bn]); bfr[6]=p[0]; bfr[7]=p[1];
                #pragma unroll
                for (int am = 0; am < 8; ++am)
                    acc[am][bn] = __builtin_amdgcn_mfma_f32_16x16x32_f16(
                        af[am], bfr, acc[am][bn], 0, 0, 0);
            }
        }
    }
    #pragma unroll
    for (int bn = 0; bn < 4; ++bn) {
        const int col = bn0 + wn0 + bn * 16 + (lane & 15);
        const float b_f = bias[col];
        #pragma unroll
        for (int am = 0; am < 8; ++am) {
            const int row_base = bm0 + am * 16 + ((lane >> 4) << 2);
            #pragma unroll
            for (int r = 0; r < 4; ++r) {
                const int row = row_base + r;
                if (row < M)
                    out[(size_t)row * N_DIM + col] = acc[am][bn][r] + b_f;
            }
        }
    }
#undef LOAD_TILE
}

extern "C" void kernel_launch(void* const* d_in, const int* in_sizes, int n_in,
                              void* d_out, int out_size, void* d_ws, size_t ws_size,
                              hipStream_t stream) {
    const float* x    = (const float*)d_in[0];
    const int*   qw   = (const int*)d_in[1];
    const int*   qz   = (const int*)d_in[2];
    const float* sc   = (const float*)d_in[3];
    const float* bias = (const float*)d_in[4];
    float*       out  = (float*)d_out;

    const int M = in_sizes[0] / K_DIM;
    const size_t x_bytes = (size_t)M * K_DIM * 2;
    const size_t w_bytes = (size_t)N_DIM * K_DIM * 2;

    if (ws_size >= x_bytes + w_bytes && (M % 128) == 0) {
        ushort* xf = (ushort*)d_ws;
        f16x8*  Wf = (f16x8*)((char*)d_ws + x_bytes);
        cvt_x_kernel<<<dim3(2048), dim3(256), 0, stream>>>(x, xf, (M * K_DIM) / 8);
        dequant_w_kernel<<<dim3(WORDS_N / 8, K_DIM / 64), dim3(256), 0, stream>>>(qw, qz, sc, Wf);
        const int nwg = (N_DIM / 128) * (M / 128);   // 86 x 16 = 1376, %8==0
        awq_gemm_pipe<<<dim3(nwg), dim3(256), 0, stream>>>(xf, Wf, bias, out, M, nwg);
    } else if (ws_size >= x_bytes) {
        ushort* xf = (ushort*)d_ws;
        const int mtiles = (M + BM - 1) / BM;
        cvt_x_kernel<<<dim3(2048), dim3(256), 0, stream>>>(x, xf, (M * K_DIM) / 8);
        awq_gemm_fused<true><<<dim3(N_DIM / BN, mtiles), dim3(256), 0, stream>>>(
            xf, qw, qz, sc, bias, out, M);
    } else {
        const int mtiles = (M + BM - 1) / BM;
        awq_gemm_fused<false><<<dim3(N_DIM / BN, mtiles), dim3(256), 0, stream>>>(
            x, qw, qz, sc, bias, out, M);
    }
}

// Round 12
// 258.376 us; speedup vs baseline: 1.3536x; 1.0018x over previous
//
#include <hip/hip_runtime.h>
#include <stdint.h>

#define K_DIM 4096
#define N_DIM 11008
#define WORDS_N 1376          // N_DIM / 8 packed words
#define BM 128
#define BN 256
#define BK 64
#define ASTR 72               // fused-fallback As stride
#define WSTR 68               // fused-fallback Wq stride (ints)

typedef _Float16 f16x2 __attribute__((ext_vector_type(2)));
typedef _Float16 f16x8 __attribute__((ext_vector_type(8)));
typedef float    f32x4 __attribute__((ext_vector_type(4)));
typedef float    f32x8 __attribute__((ext_vector_type(8)));
typedef int      int4v __attribute__((ext_vector_type(4)));
typedef int      int2v __attribute__((ext_vector_type(2)));
typedef unsigned short ushort;
typedef unsigned int u32;

__device__ __forceinline__ f16x2 dq2(int wa, int wb, int shf, f16x2 s2, f16x2 c2) {
    u32 t0 = ((u32)wa >> shf) & 0xFu;
    u32 t1 = ((u32)wb >> shf) & 0xFu;
    u32 h  = 0x64006400u | t0 | (t1 << 16);
    f16x2 q = __builtin_bit_cast(f16x2, h);
    q = q - (f16x2)((_Float16)1024.0f);
    return q * s2 + c2;
}

__device__ __forceinline__ void gload16(const void* g, void* l) {
    __builtin_amdgcn_global_load_lds(
        (const __attribute__((address_space(1))) unsigned int*)g,
        (__attribute__((address_space(3))) unsigned int*)l, 16, 0, 0);
}

// ---- pre-pass 1: x f32 -> fp16 ----
__global__ __launch_bounds__(256)
void cvt_x_kernel(const float* __restrict__ x, ushort* __restrict__ xf, int n8) {
    for (int i = blockIdx.x * 256 + threadIdx.x; i < n8; i += gridDim.x * 256) {
        f32x4 a = *(const f32x4*)(x + (size_t)i * 8);
        f32x4 b = *(const f32x4*)(x + (size_t)i * 8 + 4);
        int4v o;
        o[0] = __builtin_bit_cast(int, __builtin_amdgcn_cvt_pkrtz(a[0], a[1]));
        o[1] = __builtin_bit_cast(int, __builtin_amdgcn_cvt_pkrtz(a[2], a[3]));
        o[2] = __builtin_bit_cast(int, __builtin_amdgcn_cvt_pkrtz(b[0], b[1]));
        o[3] = __builtin_bit_cast(int, __builtin_amdgcn_cvt_pkrtz(b[2], b[3]));
        *(int4v*)(xf + (size_t)i * 8) = o;
    }
}

// ---- pre-pass 2: dequant qweight -> W in MFMA-fragment order ----
// unit = f16x8. layout: unit_idx = (ntile*512 + kidx)*16 + (col&15)
__global__ __launch_bounds__(256)
void dequant_w_kernel(const int* __restrict__ qw,
                      const int* __restrict__ qz,
                      const float* __restrict__ sc,
                      f16x8* __restrict__ Wf)
{
    __shared__ __align__(16) int Wq[8 * WSTR];
    const int t  = threadIdx.x;
    const int w0 = blockIdx.x * 8;
    const int n0 = blockIdx.x * 64;
    const int k0 = blockIdx.y * 64;
    {
        const int k  = t >> 2;
        const int wp = (t & 3) * 2;
        const int2v v = *(const int2v*)(qw + (size_t)(k0 + k) * WORDS_N + w0 + wp);
        Wq[(wp + 0) * WSTR + k] = v[0];
        Wq[(wp + 1) * WSTR + k] = v[1];
    }
    __syncthreads();

    const int n   = t & 63;
    const int oc0 = t >> 6;
    const int w   = n >> 3;
    const int j   = n & 7;
    const int shf = ((j & 1) << 4) + ((j >> 1) << 2);
    const int g   = k0 >> 7;

    const int   nn = n0 + n;
    const float s  = sc[(size_t)g * N_DIM + nn];
    const int   zq = (qz[(size_t)g * WORDS_N + w0 + w] >> shf) & 0xF;
    const float nz = -(float)zq * s;

    #pragma unroll
    for (int oo = 0; oo < 2; ++oo) {
        const int oc = oc0 + oo * 4;
        const int4v lo = *(const int4v*)&Wq[w * WSTR + oc * 8];
        const int4v hi = *(const int4v*)&Wq[w * WSTR + oc * 8 + 4];
        f16x8 h;
        #pragma unroll
        for (int r = 0; r < 4; ++r)
            h[r] = (_Float16)((float)((lo[r] >> shf) & 0xF) * s + nz);
        #pragma unroll
        for (int r = 0; r < 4; ++r)
            h[4 + r] = (_Float16)((float)((hi[r] >> shf) & 0xF) * s + nz);
        const size_t kidx = (size_t)((k0 >> 3) + oc);
        Wf[((size_t)(nn >> 4) * 512 + kidx) * 16 + (nn & 15)] = h;
    }
}

// ---- main GEMM: A via gload_lds+swizzle pipeline, B double-buffered in regs
//      from fragment-ordered Wf (coalesced 1KB L2 reads). 3 blocks/CU. ----
__global__ __launch_bounds__(256, 3)
void awq_gemm_pipe(const ushort* __restrict__ x16,
                   const f16x8* __restrict__ Wf,
                   const float* __restrict__ bias,
                   float* __restrict__ out,
                   int M, int nwg)
{
    __shared__ __align__(16) _Float16 As[2][128 * 64];  // 2 x 16 KB, A only

    const int tid  = threadIdx.x;
    const int lane = tid & 63;
    const int wid  = tid >> 6;

    // XCD swizzle: nwg divisible by 8; consecutive logical g share bx (B panel).
    const int hh  = blockIdx.x;
    const int g   = (hh & 7) * (nwg >> 3) + (hh >> 3);
    const int bx  = g >> 4;          // N tile
    const int by  = g & 15;          // M tile
    const int bn0 = bx * 128;
    const int bm0 = by * 128;

    const int wm0 = (wid >> 1) * 64;
    const int wn0 = (wid & 1) * 64;

    // A staging (proven round 10): linear LDS dest, pre-swizzled global slot
    const int srow = lane >> 3;
    const int slot = (lane & 7) ^ srow;
    const ushort* aSrc = x16 + (size_t)(bm0 + wid * 32 + srow) * K_DIM + slot * 8;

#define STAGE_A(BUF, K0)                                                        \
    {                                                                           \
        _Pragma("unroll")                                                       \
        for (int jj = 0; jj < 4; ++jj)                                          \
            gload16(aSrc + (size_t)(K0) + jj * 8 * K_DIM,                       \
                    &As[BUF][(wid * 32 + jj * 8) * 64]);                        \
    }

    // B fragment bases: ntile = (bn0+wn0)/16 + n ; unit idx = ntile*8192 + T*128 + ks*64 + lane
    size_t nb[4];
    #pragma unroll
    for (int n = 0; n < 4; ++n)
        nb[n] = ((size_t)((bn0 + wn0) >> 4) + n) * 8192 + lane;

    f32x4 acc[4][4];
    #pragma unroll
    for (int i = 0; i < 4; ++i)
        #pragma unroll
        for (int j = 0; j < 4; ++j)
            acc[i][j] = (f32x4){0.f, 0.f, 0.f, 0.f};

    f16x8 BR0[8], BR1[8];
    const int NT = K_DIM / 64;  // 64

#define LOADB(DST, T)                                                           \
    {                                                                           \
        const size_t koff = (size_t)(T) * 128;                                  \
        _Pragma("unroll")                                                       \
        for (int jj = 0; jj < 8; ++jj)                                          \
            DST[jj] = Wf[nb[jj & 3] + koff + (size_t)(jj >> 2) * 64];           \
    }

    const int rd_sw = (lane & 7) << 4;
    const int rrow  = lane & 15;

    // prologue: A[0], B[0], A[1] (issue order matters for vmcnt counting)
    STAGE_A(0, 0);
    LOADB(BR0, 0);
    STAGE_A(1, 64);

#define ITER(T, BRD, BWR)                                                          \
    {                                                                              \
        asm volatile("s_waitcnt vmcnt(12)" ::: "memory");                          \
        __builtin_amdgcn_sched_barrier(0);                                         \
        __builtin_amdgcn_s_barrier();                                              \
        __builtin_amdgcn_sched_barrier(0);                                         \
        { const int tn = ((T) + 1 < NT) ? (T) + 1 : NT - 1; LOADB(BWR, tn); }      \
        __builtin_amdgcn_sched_barrier(0);                                         \
        const char* aB = (const char*)&As[(T) & 1][0];                             \
        _Pragma("unroll")                                                          \
        for (int ks = 0; ks < 2; ++ks) {                                           \
            const int kb = ks * 64 + ((lane >> 4) << 4);                           \
            f16x8 af[4];                                                           \
            _Pragma("unroll")                                                      \
            for (int m = 0; m < 4; ++m)                                            \
                af[m] = *(const f16x8*)(aB + (wm0 + m * 16 + rrow) * 128 + (kb ^ rd_sw)); \
            __builtin_amdgcn_s_setprio(1);                                         \
            _Pragma("unroll")                                                      \
            for (int m = 0; m < 4; ++m)                                            \
                _Pragma("unroll")                                                  \
                for (int n = 0; n < 4; ++n)                                        \
                    acc[m][n] = __builtin_amdgcn_mfma_f32_16x16x32_f16(            \
                        af[m], BRD[ks * 4 + n], acc[m][n], 0, 0, 0);               \
            __builtin_amdgcn_s_setprio(0);                                         \
        }                                                                          \
        __builtin_amdgcn_sched_barrier(0);                                         \
        __builtin_amdgcn_s_barrier();                                              \
        __builtin_amdgcn_sched_barrier(0);                                         \
        { const int t2 = ((T) + 2 < NT) ? (T) + 2 : NT - 1; STAGE_A((T) & 1, t2 * 64); } \
    }

    for (int t = 0; t < NT; t += 2) {
        ITER(t,     BR0, BR1);
        ITER(t + 1, BR1, BR0);
    }
#undef ITER
#undef LOADB
#undef STAGE_A

    // epilogue: C/D col=lane&15, row=(lane>>4)*4+r (m89-verified)
    #pragma unroll
    for (int n = 0; n < 4; ++n) {
        const int col = bn0 + wn0 + n * 16 + (lane & 15);
        const float b_f = bias[col];
        #pragma unroll
        for (int m = 0; m < 4; ++m) {
            const int row_base = bm0 + wm0 + m * 16 + ((lane >> 4) << 2);
            #pragma unroll
            for (int r = 0; r < 4; ++r) {
                const int row = row_base + r;
                if (row < M)
                    out[(size_t)row * N_DIM + col] = acc[m][n][r] + b_f;
            }
        }
    }
}

// ---- fallback: fused kernel (proven rounds 6-8) ----
template <bool XF16>
__global__ __launch_bounds__(256, 2)
void awq_gemm_fused(const void* __restrict__ xin,
                    const int* __restrict__ qw,
                    const int* __restrict__ qz,
                    const float* __restrict__ sc,
                    const float* __restrict__ bias,
                    float* __restrict__ out,
                    int M)
{
    __shared__ __align__(16) _Float16 Asf[BM * ASTR];
    __shared__ __align__(16) int Wq[32 * WSTR];

    const int tid  = threadIdx.x;
    const int lane = tid & 63;
    const int wid  = tid >> 6;
    const int bn0 = blockIdx.x * BN;
    const int bm0 = blockIdx.y * BM;
    const int w0  = bn0 >> 3;
    const int wn0 = wid * 64;
    const int a_row = tid >> 3;
    const int a_col = (tid & 7) * 8;
    const int b_krow = tid >> 2;
    const int b_wg   = (tid & 3) * 4;

    int n_loc[4], w_loc[4], shf[4];
    #pragma unroll
    for (int bn = 0; bn < 4; ++bn) {
        n_loc[bn] = wn0 + bn * 16 + (lane & 15);
        w_loc[bn] = n_loc[bn] >> 3;
        int j = n_loc[bn] & 7;
        shf[bn] = ((j & 1) << 4) + ((j >> 1) << 2);
    }
    f16x2 s2[4], c2[4];
    f32x4 acc[8][4];
    #pragma unroll
    for (int i = 0; i < 8; ++i)
        #pragma unroll
        for (int j = 0; j < 4; ++j)
            acc[i][j] = (f32x4){0.f, 0.f, 0.f, 0.f};
    int4v aReg16[4];
    f32x8 aReg32[4];
    int4v bReg[2];
    const ushort* x16 = (const ushort*)xin;
    const float*  x32 = (const float*)xin;

#define LOAD_TILE(K0)                                                                  \
    {                                                                                  \
        _Pragma("unroll")                                                              \
        for (int i = 0; i < 4; ++i) {                                                  \
            int row = bm0 + a_row + i * 32;                                            \
            if constexpr (XF16) {                                                      \
                if (row < M)                                                           \
                    aReg16[i] = *(const int4v*)(x16 + (size_t)row * K_DIM + (K0) + a_col); \
                else aReg16[i] = (int4v){0, 0, 0, 0};                                  \
            } else {                                                                   \
                if (row < M)                                                           \
                    aReg32[i] = *(const f32x8*)(x32 + (size_t)row * K_DIM + (K0) + a_col); \
                else aReg32[i] = (f32x8){0.f,0.f,0.f,0.f,0.f,0.f,0.f,0.f};             \
            }                                                                          \
        }                                                                              \
        bReg[0] = *(const int4v*)(qw + (size_t)((K0) + b_krow) * WORDS_N + w0 + b_wg);      \
        bReg[1] = *(const int4v*)(qw + (size_t)((K0) + b_krow) * WORDS_N + w0 + b_wg + 16); \
    }

    LOAD_TILE(0);
    const int NT = K_DIM / BK;
    for (int t = 0; t < NT; ++t) {
        const int k0 = t * BK;
        __syncthreads();
        #pragma unroll
        for (int i = 0; i < 4; ++i) {
            if constexpr (XF16) {
                *(int4v*)&Asf[(a_row + i * 32) * ASTR + a_col] = aReg16[i];
            } else {
                f16x8 hh2;
                #pragma unroll
                for (int r = 0; r < 4; ++r) {
                    f16x2 p = __builtin_bit_cast(f16x2,
                        __builtin_amdgcn_cvt_pkrtz(aReg32[i][2*r], aReg32[i][2*r+1]));
                    hh2[2*r] = p[0]; hh2[2*r+1] = p[1];
                }
                *(f16x8*)&Asf[(a_row + i * 32) * ASTR + a_col] = hh2;
            }
        }
        #pragma unroll
        for (int c = 0; c < 4; ++c) {
            Wq[(b_wg + c) * WSTR + b_krow]      = bReg[0][c];
            Wq[(b_wg + 16 + c) * WSTR + b_krow] = bReg[1][c];
        }
        __syncthreads();
        if (t + 1 < NT) LOAD_TILE(k0 + BK);
        if ((t & 1) == 0) {
            const int gg = k0 >> 7;
            #pragma unroll
            for (int bn = 0; bn < 4; ++bn) {
                float s = sc[(size_t)gg * N_DIM + bn0 + n_loc[bn]];
                int zq  = (qz[(size_t)gg * WORDS_N + w0 + w_loc[bn]] >> shf[bn]) & 0xF;
                _Float16 sh = (_Float16)s;
                _Float16 nz = (_Float16)(-(float)zq * s);
                s2[bn] = (f16x2){sh, sh};
                c2[bn] = (f16x2){nz, nz};
            }
        }
        #pragma unroll
        for (int ks = 0; ks < 2; ++ks) {
            const int kk = ks * 32 + (lane >> 4) * 8;
            f16x8 af[8];
            #pragma unroll
            for (int am = 0; am < 8; ++am)
                af[am] = *(const f16x8*)&Asf[(am * 16 + (lane & 15)) * ASTR + kk];
            #pragma unroll
            for (int bn = 0; bn < 4; ++bn) {
                const int4v lo = *(const int4v*)&Wq[w_loc[bn] * WSTR + kk];
                const int4v hi = *(const int4v*)&Wq[w_loc[bn] * WSTR + kk + 4];
                f16x8 bfr;
                f16x2 p;
                p = dq2(lo[0], lo[1], shf[bn], s2[bn], c2[bn]); bfr[0]=p[0]; bfr[1]=p[1];
                p = dq2(lo[2], lo[3], shf[bn], s2[bn], c2[bn]); bfr[2]=p[0]; bfr[3]=p[1];
                p = dq2(hi[0], hi[1], shf[bn], s2[bn], c2[bn]); bfr[4]=p[0]; bfr[5]=p[1];
                p = dq2(hi[2], hi[3], shf[bn], s2[bn], c2[bn]); bfr[6]=p[0]; bfr[7]=p[1];
                #pragma unroll
                for (int am = 0; am < 8; ++am)
                    acc[am][bn] = __builtin_amdgcn_mfma_f32_16x16x32_f16(
                        af[am], bfr, acc[am][bn], 0, 0, 0);
            }
        }
    }
    #pragma unroll
    for (int bn = 0; bn < 4; ++bn) {
        const int col = bn0 + wn0 + bn * 16 + (lane & 15);
        const float b_f = bias[col];
        #pragma unroll
        for (int am = 0; am < 8; ++am) {
            const int row_base = bm0 + am * 16 + ((lane >> 4) << 2);
            #pragma unroll
            for (int r = 0; r < 4; ++r) {
                const int row = row_base + r;
                if (row < M)
                    out[(size_t)row * N_DIM + col] = acc[am][bn][r] + b_f;
            }
        }
    }
#undef LOAD_TILE
}

extern "C" void kernel_launch(void* const* d_in, const int* in_sizes, int n_in,
                              void* d_out, int out_size, void* d_ws, size_t ws_size,
                              hipStream_t stream) {
    const float* x    = (const float*)d_in[0];
    const int*   qw   = (const int*)d_in[1];
    const int*   qz   = (const int*)d_in[2];
    const float* sc   = (const float*)d_in[3];
    const float* bias = (const float*)d_in[4];
    float*       out  = (float*)d_out;

    const int M = in_sizes[0] / K_DIM;
    const size_t x_bytes = (size_t)M * K_DIM * 2;
    const size_t w_bytes = (size_t)N_DIM * K_DIM * 2;

    if (ws_size >= x_bytes + w_bytes && (M % 128) == 0) {
        ushort* xf = (ushort*)d_ws;
        f16x8*  Wf = (f16x8*)((char*)d_ws + x_bytes);
        cvt_x_kernel<<<dim3(2048), dim3(256), 0, stream>>>(x, xf, (M * K_DIM) / 8);
        dequant_w_kernel<<<dim3(WORDS_N / 8, K_DIM / 64), dim3(256), 0, stream>>>(qw, qz, sc, Wf);
        const int nwg = (N_DIM / 128) * (M / 128);   // 86 x 16 = 1376, %8==0
        awq_gemm_pipe<<<dim3(nwg), dim3(256), 0, stream>>>(xf, Wf, bias, out, M, nwg);
    } else if (ws_size >= x_bytes) {
        ushort* xf = (ushort*)d_ws;
        const int mtiles = (M + BM - 1) / BM;
        cvt_x_kernel<<<dim3(2048), dim3(256), 0, stream>>>(x, xf, (M * K_DIM) / 8);
        awq_gemm_fused<true><<<dim3(N_DIM / BN, mtiles), dim3(256), 0, stream>>>(
            xf, qw, qz, sc, bias, out, M);
    } else {
        const int mtiles = (M + BM - 1) / BM;
        awq_gemm_fused<false><<<dim3(N_DIM / BN, mtiles), dim3(256), 0, stream>>>(
            x, qw, qz, sc, bias, out, M);
    }
}

// Round 13
// 250.554 us; speedup vs baseline: 1.3958x; 1.0312x over previous
//
#include <hip/hip_runtime.h>
#include <stdint.h>

#define K_DIM 4096
#define N_DIM 11008
#define WORDS_N 1376          // N_DIM / 8 packed words
#define BM 128
#define BN 256
#define BK 64
#define ASTR 72               // fused-fallback As stride
#define WSTR 68               // fused-fallback Wq stride (ints)

typedef _Float16 f16x2 __attribute__((ext_vector_type(2)));
typedef _Float16 f16x8 __attribute__((ext_vector_type(8)));
typedef float    f32x4 __attribute__((ext_vector_type(4)));
typedef float    f32x8 __attribute__((ext_vector_type(8)));
typedef int      int4v __attribute__((ext_vector_type(4)));
typedef int      int2v __attribute__((ext_vector_type(2)));
typedef unsigned short ushort;
typedef unsigned int u32;

__device__ __forceinline__ f16x2 dq2(int wa, int wb, int shf, f16x2 s2, f16x2 c2) {
    u32 t0 = ((u32)wa >> shf) & 0xFu;
    u32 t1 = ((u32)wb >> shf) & 0xFu;
    u32 h  = 0x64006400u | t0 | (t1 << 16);
    f16x2 q = __builtin_bit_cast(f16x2, h);
    q = q - (f16x2)((_Float16)1024.0f);
    return q * s2 + c2;
}

__device__ __forceinline__ void gload16(const void* g, void* l) {
    __builtin_amdgcn_global_load_lds(
        (const __attribute__((address_space(1))) unsigned int*)g,
        (__attribute__((address_space(3))) unsigned int*)l, 16, 0, 0);
}

// ---- pre-pass 1: x f32 -> fp16 ----
__global__ __launch_bounds__(256)
void cvt_x_kernel(const float* __restrict__ x, ushort* __restrict__ xf, int n8) {
    for (int i = blockIdx.x * 256 + threadIdx.x; i < n8; i += gridDim.x * 256) {
        f32x4 a = *(const f32x4*)(x + (size_t)i * 8);
        f32x4 b = *(const f32x4*)(x + (size_t)i * 8 + 4);
        int4v o;
        o[0] = __builtin_bit_cast(int, __builtin_amdgcn_cvt_pkrtz(a[0], a[1]));
        o[1] = __builtin_bit_cast(int, __builtin_amdgcn_cvt_pkrtz(a[2], a[3]));
        o[2] = __builtin_bit_cast(int, __builtin_amdgcn_cvt_pkrtz(b[0], b[1]));
        o[3] = __builtin_bit_cast(int, __builtin_amdgcn_cvt_pkrtz(b[2], b[3]));
        *(int4v*)(xf + (size_t)i * 8) = o;
    }
}

// ---- pre-pass 2: dequant qweight -> W in MFMA-fragment order ----
// unit = f16x8. layout: unit_idx = (ntile*512 + kidx)*16 + (col&15)
__global__ __launch_bounds__(256)
void dequant_w_kernel(const int* __restrict__ qw,
                      const int* __restrict__ qz,
                      const float* __restrict__ sc,
                      f16x8* __restrict__ Wf)
{
    __shared__ __align__(16) int Wq[8 * WSTR];
    const int t  = threadIdx.x;
    const int w0 = blockIdx.x * 8;
    const int n0 = blockIdx.x * 64;
    const int k0 = blockIdx.y * 64;
    {
        const int k  = t >> 2;
        const int wp = (t & 3) * 2;
        const int2v v = *(const int2v*)(qw + (size_t)(k0 + k) * WORDS_N + w0 + wp);
        Wq[(wp + 0) * WSTR + k] = v[0];
        Wq[(wp + 1) * WSTR + k] = v[1];
    }
    __syncthreads();

    const int n   = t & 63;
    const int oc0 = t >> 6;
    const int w   = n >> 3;
    const int j   = n & 7;
    const int shf = ((j & 1) << 4) + ((j >> 1) << 2);
    const int g   = k0 >> 7;

    const int   nn = n0 + n;
    const float s  = sc[(size_t)g * N_DIM + nn];
    const int   zq = (qz[(size_t)g * WORDS_N + w0 + w] >> shf) & 0xF;
    const float nz = -(float)zq * s;

    #pragma unroll
    for (int oo = 0; oo < 2; ++oo) {
        const int oc = oc0 + oo * 4;
        const int4v lo = *(const int4v*)&Wq[w * WSTR + oc * 8];
        const int4v hi = *(const int4v*)&Wq[w * WSTR + oc * 8 + 4];
        f16x8 h;
        #pragma unroll
        for (int r = 0; r < 4; ++r)
            h[r] = (_Float16)((float)((lo[r] >> shf) & 0xF) * s + nz);
        #pragma unroll
        for (int r = 0; r < 4; ++r)
            h[4 + r] = (_Float16)((float)((hi[r] >> shf) & 0xF) * s + nz);
        const size_t kidx = (size_t)((k0 >> 3) + oc);
        Wf[((size_t)(nn >> 4) * 512 + kidx) * 16 + (nn & 15)] = h;
    }
}

// ---- main GEMM: triple-buffered A (gload_lds+swizzle), ONE barrier per K-tile,
//      B double-buffered in regs from fragment-ordered Wf ----
__global__ __launch_bounds__(256, 2)
void awq_gemm_pipe(const ushort* __restrict__ x16,
                   const f16x8* __restrict__ Wf,
                   const float* __restrict__ bias,
                   float* __restrict__ out,
                   int M, int nwg)
{
    __shared__ __align__(16) _Float16 As[3][128 * 64];  // 3 x 16 KB, A only

    const int tid  = threadIdx.x;
    const int lane = tid & 63;
    const int wid  = tid >> 6;

    // XCD swizzle: nwg divisible by 8; consecutive logical g share bx (B panel).
    const int hh  = blockIdx.x;
    const int g   = (hh & 7) * (nwg >> 3) + (hh >> 3);
    const int bx  = g >> 4;          // N tile
    const int by  = g & 15;          // M tile
    const int bn0 = bx * 128;
    const int bm0 = by * 128;

    const int wm0 = (wid >> 1) * 64;
    const int wn0 = (wid & 1) * 64;

    // A staging: linear LDS dest, pre-swizzled global slot (proven round 10)
    const int srow = lane >> 3;
    const int slot = (lane & 7) ^ srow;
    const ushort* aSrc = x16 + (size_t)(bm0 + wid * 32 + srow) * K_DIM + slot * 8;

#define STAGE_A(BUFP, K0)                                                       \
    {                                                                           \
        _Pragma("unroll")                                                       \
        for (int jj = 0; jj < 4; ++jj)                                          \
            gload16(aSrc + (size_t)(K0) + jj * 8 * K_DIM,                       \
                    (BUFP) + (wid * 32 + jj * 8) * 64);                         \
    }

    // B fragment bases: unit idx = ntile*8192 + T*128 + ks*64 + lane
    size_t nb[4];
    #pragma unroll
    for (int n = 0; n < 4; ++n)
        nb[n] = ((size_t)((bn0 + wn0) >> 4) + n) * 8192 + lane;

    f32x4 acc[4][4];
    #pragma unroll
    for (int i = 0; i < 4; ++i)
        #pragma unroll
        for (int j = 0; j < 4; ++j)
            acc[i][j] = (f32x4){0.f, 0.f, 0.f, 0.f};

    f16x8 BR0[8], BR1[8];
    const int NT = K_DIM / 64;  // 64

#define LOADB(DST, T)                                                           \
    {                                                                           \
        const size_t koff = (size_t)(T) * 128;                                  \
        _Pragma("unroll")                                                       \
        for (int jj = 0; jj < 8; ++jj)                                          \
            DST[jj] = Wf[nb[jj & 3] + koff + (size_t)(jj >> 2) * 64];           \
    }

    const int rd_sw = (lane & 7) << 4;
    const int rrow  = lane & 15;

    // prologue: A0 -> buf0, B0 -> regs, A1 -> buf1 (issue order = vmcnt order)
    STAGE_A(&As[0][0], 0);
    LOADB(BR0, 0);
    STAGE_A(&As[1][0], 64);

    int rd = 0;   // buffer holding tile T (cycles 0,1,2)

    // ITER: ONE barrier per K-tile. Safety: STAGE_A at end of iter T writes
    // buf[(T+2)%3] = buf[(T-1)%3]... wait: (T+2)%3 == (T-1)%3; its readers ran
    // in iter T-1 and all passed THIS iter's top barrier before we stage.
    // vmcnt(12) at top of T waits A(T) (12 newer loads: B(T)8 + A(T+1)4).
#define ITER(T, BRD, BWR)                                                          \
    {                                                                              \
        asm volatile("s_waitcnt vmcnt(12)" ::: "memory");                          \
        __builtin_amdgcn_sched_barrier(0);                                         \
        __builtin_amdgcn_s_barrier();                                              \
        __builtin_amdgcn_sched_barrier(0);                                         \
        { const int tn = ((T) + 1 < NT) ? (T) + 1 : NT - 1; LOADB(BWR, tn); }      \
        __builtin_amdgcn_sched_barrier(0);                                         \
        const char* aB = (const char*)&As[rd][0];                                  \
        _Pragma("unroll")                                                          \
        for (int ks = 0; ks < 2; ++ks) {                                           \
            const int kb = ks * 64 + ((lane >> 4) << 4);                           \
            f16x8 af[4];                                                           \
            _Pragma("unroll")                                                      \
            for (int m = 0; m < 4; ++m)                                            \
                af[m] = *(const f16x8*)(aB + (wm0 + m * 16 + rrow) * 128 + (kb ^ rd_sw)); \
            __builtin_amdgcn_s_setprio(1);                                         \
            _Pragma("unroll")                                                      \
            for (int m = 0; m < 4; ++m)                                            \
                _Pragma("unroll")                                                  \
                for (int n = 0; n < 4; ++n)                                        \
                    acc[m][n] = __builtin_amdgcn_mfma_f32_16x16x32_f16(            \
                        af[m], BRD[ks * 4 + n], acc[m][n], 0, 0, 0);               \
            __builtin_amdgcn_s_setprio(0);                                         \
        }                                                                          \
        {                                                                          \
            const int stg = (rd >= 1) ? rd - 1 : 2;        /* (rd+2)%3 */          \
            const int t2  = ((T) + 2 < NT) ? (T) + 2 : NT - 1;                     \
            STAGE_A(&As[stg][0], t2 * 64);                                         \
        }                                                                          \
        rd = (rd < 2) ? rd + 1 : 0;                                                \
    }

    for (int t = 0; t < NT; t += 2) {
        ITER(t,     BR0, BR1);
        ITER(t + 1, BR1, BR0);
    }
#undef ITER
#undef LOADB
#undef STAGE_A

    // epilogue: C/D col=lane&15, row=(lane>>4)*4+r (m89-verified)
    #pragma unroll
    for (int n = 0; n < 4; ++n) {
        const int col = bn0 + wn0 + n * 16 + (lane & 15);
        const float b_f = bias[col];
        #pragma unroll
        for (int m = 0; m < 4; ++m) {
            const int row_base = bm0 + wm0 + m * 16 + ((lane >> 4) << 2);
            #pragma unroll
            for (int r = 0; r < 4; ++r) {
                const int row = row_base + r;
                if (row < M)
                    out[(size_t)row * N_DIM + col] = acc[m][n][r] + b_f;
            }
        }
    }
}

// ---- fallback: fused kernel (proven rounds 6-8) ----
template <bool XF16>
__global__ __launch_bounds__(256, 2)
void awq_gemm_fused(const void* __restrict__ xin,
                    const int* __restrict__ qw,
                    const int* __restrict__ qz,
                    const float* __restrict__ sc,
                    const float* __restrict__ bias,
                    float* __restrict__ out,
                    int M)
{
    __shared__ __align__(16) _Float16 Asf[BM * ASTR];
    __shared__ __align__(16) int Wq[32 * WSTR];

    const int tid  = threadIdx.x;
    const int lane = tid & 63;
    const int wid  = tid >> 6;
    const int bn0 = blockIdx.x * BN;
    const int bm0 = blockIdx.y * BM;
    const int w0  = bn0 >> 3;
    const int wn0 = wid * 64;
    const int a_row = tid >> 3;
    const int a_col = (tid & 7) * 8;
    const int b_krow = tid >> 2;
    const int b_wg   = (tid & 3) * 4;

    int n_loc[4], w_loc[4], shf[4];
    #pragma unroll
    for (int bn = 0; bn < 4; ++bn) {
        n_loc[bn] = wn0 + bn * 16 + (lane & 15);
        w_loc[bn] = n_loc[bn] >> 3;
        int j = n_loc[bn] & 7;
        shf[bn] = ((j & 1) << 4) + ((j >> 1) << 2);
    }
    f16x2 s2[4], c2[4];
    f32x4 acc[8][4];
    #pragma unroll
    for (int i = 0; i < 8; ++i)
        #pragma unroll
        for (int j = 0; j < 4; ++j)
            acc[i][j] = (f32x4){0.f, 0.f, 0.f, 0.f};
    int4v aReg16[4];
    f32x8 aReg32[4];
    int4v bReg[2];
    const ushort* x16 = (const ushort*)xin;
    const float*  x32 = (const float*)xin;

#define LOAD_TILE(K0)                                                                  \
    {                                                                                  \
        _Pragma("unroll")                                                              \
        for (int i = 0; i < 4; ++i) {                                                  \
            int row = bm0 + a_row + i * 32;                                            \
            if constexpr (XF16) {                                                      \
                if (row < M)                                                           \
                    aReg16[i] = *(const int4v*)(x16 + (size_t)row * K_DIM + (K0) + a_col); \
                else aReg16[i] = (int4v){0, 0, 0, 0};                                  \
            } else {                                                                   \
                if (row < M)                                                           \
                    aReg32[i] = *(const f32x8*)(x32 + (size_t)row * K_DIM + (K0) + a_col); \
                else aReg32[i] = (f32x8){0.f,0.f,0.f,0.f,0.f,0.f,0.f,0.f};             \
            }                                                                          \
        }                                                                              \
        bReg[0] = *(const int4v*)(qw + (size_t)((K0) + b_krow) * WORDS_N + w0 + b_wg);      \
        bReg[1] = *(const int4v*)(qw + (size_t)((K0) + b_krow) * WORDS_N + w0 + b_wg + 16); \
    }

    LOAD_TILE(0);
    const int NT = K_DIM / BK;
    for (int t = 0; t < NT; ++t) {
        const int k0 = t * BK;
        __syncthreads();
        #pragma unroll
        for (int i = 0; i < 4; ++i) {
            if constexpr (XF16) {
                *(int4v*)&Asf[(a_row + i * 32) * ASTR + a_col] = aReg16[i];
            } else {
                f16x8 hh2;
                #pragma unroll
                for (int r = 0; r < 4; ++r) {
                    f16x2 p = __builtin_bit_cast(f16x2,
                        __builtin_amdgcn_cvt_pkrtz(aReg32[i][2*r], aReg32[i][2*r+1]));
                    hh2[2*r] = p[0]; hh2[2*r+1] = p[1];
                }
                *(f16x8*)&Asf[(a_row + i * 32) * ASTR + a_col] = hh2;
            }
        }
        #pragma unroll
        for (int c = 0; c < 4; ++c) {
            Wq[(b_wg + c) * WSTR + b_krow]      = bReg[0][c];
            Wq[(b_wg + 16 + c) * WSTR + b_krow] = bReg[1][c];
        }
        __syncthreads();
        if (t + 1 < NT) LOAD_TILE(k0 + BK);
        if ((t & 1) == 0) {
            const int gg = k0 >> 7;
            #pragma unroll
            for (int bn = 0; bn < 4; ++bn) {
                float s = sc[(size_t)gg * N_DIM + bn0 + n_loc[bn]];
                int zq  = (qz[(size_t)gg * WORDS_N + w0 + w_loc[bn]] >> shf[bn]) & 0xF;
                _Float16 sh = (_Float16)s;
                _Float16 nz = (_Float16)(-(float)zq * s);
                s2[bn] = (f16x2){sh, sh};
                c2[bn] = (f16x2){nz, nz};
            }
        }
        #pragma unroll
        for (int ks = 0; ks < 2; ++ks) {
            const int kk = ks * 32 + (lane >> 4) * 8;
            f16x8 af[8];
            #pragma unroll
            for (int am = 0; am < 8; ++am)
                af[am] = *(const f16x8*)&Asf[(am * 16 + (lane & 15)) * ASTR + kk];
            #pragma unroll
            for (int bn = 0; bn < 4; ++bn) {
                const int4v lo = *(const int4v*)&Wq[w_loc[bn] * WSTR + kk];
                const int4v hi = *(const int4v*)&Wq[w_loc[bn] * WSTR + kk + 4];
                f16x8 bfr;
                f16x2 p;
                p = dq2(lo[0], lo[1], shf[bn], s2[bn], c2[bn]); bfr[0]=p[0]; bfr[1]=p[1];
                p = dq2(lo[2], lo[3], shf[bn], s2[bn], c2[bn]); bfr[2]=p[0]; bfr[3]=p[1];
                p = dq2(hi[0], hi[1], shf[bn], s2[bn], c2[bn]); bfr[4]=p[0]; bfr[5]=p[1];
                p = dq2(hi[2], hi[3], shf[bn], s2[bn], c2[bn]); bfr[6]=p[0]; bfr[7]=p[1];
                #pragma unroll
                for (int am = 0; am < 8; ++am)
                    acc[am][bn] = __builtin_amdgcn_mfma_f32_16x16x32_f16(
                        af[am], bfr, acc[am][bn], 0, 0, 0);
            }
        }
    }
    #pragma unroll
    for (int bn = 0; bn < 4; ++bn) {
        const int col = bn0 + wn0 + bn * 16 + (lane & 15);
        const float b_f = bias[col];
        #pragma unroll
        for (int am = 0; am < 8; ++am) {
            const int row_base = bm0 + am * 16 + ((lane >> 4) << 2);
            #pragma unroll
            for (int r = 0; r < 4; ++r) {
                const int row = row_base + r;
                if (row < M)
                    out[(size_t)row * N_DIM + col] = acc[am][bn][r] + b_f;
            }
        }
    }
#undef LOAD_TILE
}

extern "C" void kernel_launch(void* const* d_in, const int* in_sizes, int n_in,
                              void* d_out, int out_size, void* d_ws, size_t ws_size,
                              hipStream_t stream) {
    const float* x    = (const float*)d_in[0];
    const int*   qw   = (const int*)d_in[1];
    const int*   qz   = (const int*)d_in[2];
    const float* sc   = (const float*)d_in[3];
    const float* bias = (const float*)d_in[4];
    float*       out  = (float*)d_out;

    const int M = in_sizes[0] / K_DIM;
    const size_t x_bytes = (size_t)M * K_DIM * 2;
    const size_t w_bytes = (size_t)N_DIM * K_DIM * 2;

    if (ws_size >= x_bytes + w_bytes && (M % 128) == 0) {
        ushort* xf = (ushort*)d_ws;
        f16x8*  Wf = (f16x8*)((char*)d_ws + x_bytes);
        cvt_x_kernel<<<dim3(2048), dim3(256), 0, stream>>>(x, xf, (M * K_DIM) / 8);
        dequant_w_kernel<<<dim3(WORDS_N / 8, K_DIM / 64), dim3(256), 0, stream>>>(qw, qz, sc, Wf);
        const int nwg = (N_DIM / 128) * (M / 128);   // 86 x 16 = 1376, %8==0
        awq_gemm_pipe<<<dim3(nwg), dim3(256), 0, stream>>>(xf, Wf, bias, out, M, nwg);
    } else if (ws_size >= x_bytes) {
        ushort* xf = (ushort*)d_ws;
        const int mtiles = (M + BM - 1) / BM;
        cvt_x_kernel<<<dim3(2048), dim3(256), 0, stream>>>(x, xf, (M * K_DIM) / 8);
        awq_gemm_fused<true><<<dim3(N_DIM / BN, mtiles), dim3(256), 0, stream>>>(
            xf, qw, qz, sc, bias, out, M);
    } else {
        const int mtiles = (M + BM - 1) / BM;
        awq_gemm_fused<false><<<dim3(N_DIM / BN, mtiles), dim3(256), 0, stream>>>(
            x, qw, qz, sc, bias, out, M);
    }
}

// Round 14
// 245.583 us; speedup vs baseline: 1.4241x; 1.0202x over previous
//
#include <hip/hip_runtime.h>
#include <stdint.h>

#define K_DIM 4096
#define N_DIM 11008
#define WORDS_N 1376          // N_DIM / 8 packed words
#define BM 128
#define BN 256
#define BK 64
#define ASTR 72               // fused-fallback As stride
#define WSTR 68               // fused-fallback Wq stride (ints)

typedef _Float16 f16x2 __attribute__((ext_vector_type(2)));
typedef _Float16 f16x8 __attribute__((ext_vector_type(8)));
typedef float    f32x4 __attribute__((ext_vector_type(4)));
typedef float    f32x8 __attribute__((ext_vector_type(8)));
typedef int      int4v __attribute__((ext_vector_type(4)));
typedef int      int2v __attribute__((ext_vector_type(2)));
typedef unsigned short ushort;
typedef unsigned int u32;

__device__ __forceinline__ f16x2 dq2(int wa, int wb, int shf, f16x2 s2, f16x2 c2) {
    u32 t0 = ((u32)wa >> shf) & 0xFu;
    u32 t1 = ((u32)wb >> shf) & 0xFu;
    u32 h  = 0x64006400u | t0 | (t1 << 16);
    f16x2 q = __builtin_bit_cast(f16x2, h);
    q = q - (f16x2)((_Float16)1024.0f);
    return q * s2 + c2;
}

__device__ __forceinline__ void gload16(const void* g, void* l) {
    __builtin_amdgcn_global_load_lds(
        (const __attribute__((address_space(1))) unsigned int*)g,
        (__attribute__((address_space(3))) unsigned int*)l, 16, 0, 0);
}

// ---- pre-pass 1: x f32 -> fp16 ----
__global__ __launch_bounds__(256)
void cvt_x_kernel(const float* __restrict__ x, ushort* __restrict__ xf, int n8) {
    for (int i = blockIdx.x * 256 + threadIdx.x; i < n8; i += gridDim.x * 256) {
        f32x4 a = *(const f32x4*)(x + (size_t)i * 8);
        f32x4 b = *(const f32x4*)(x + (size_t)i * 8 + 4);
        int4v o;
        o[0] = __builtin_bit_cast(int, __builtin_amdgcn_cvt_pkrtz(a[0], a[1]));
        o[1] = __builtin_bit_cast(int, __builtin_amdgcn_cvt_pkrtz(a[2], a[3]));
        o[2] = __builtin_bit_cast(int, __builtin_amdgcn_cvt_pkrtz(b[0], b[1]));
        o[3] = __builtin_bit_cast(int, __builtin_amdgcn_cvt_pkrtz(b[2], b[3]));
        *(int4v*)(xf + (size_t)i * 8) = o;
    }
}

// ---- pre-pass 2: dequant qweight -> W in MFMA-fragment order ----
// unit = f16x8. layout: unit_idx = (ntile*512 + kidx)*16 + (col&15)
__global__ __launch_bounds__(256)
void dequant_w_kernel(const int* __restrict__ qw,
                      const int* __restrict__ qz,
                      const float* __restrict__ sc,
                      f16x8* __restrict__ Wf)
{
    __shared__ __align__(16) int Wq[8 * WSTR];
    const int t  = threadIdx.x;
    const int w0 = blockIdx.x * 8;
    const int n0 = blockIdx.x * 64;
    const int k0 = blockIdx.y * 64;
    {
        const int k  = t >> 2;
        const int wp = (t & 3) * 2;
        const int2v v = *(const int2v*)(qw + (size_t)(k0 + k) * WORDS_N + w0 + wp);
        Wq[(wp + 0) * WSTR + k] = v[0];
        Wq[(wp + 1) * WSTR + k] = v[1];
    }
    __syncthreads();

    const int n   = t & 63;
    const int oc0 = t >> 6;
    const int w   = n >> 3;
    const int j   = n & 7;
    const int shf = ((j & 1) << 4) + ((j >> 1) << 2);
    const int g   = k0 >> 7;

    const int   nn = n0 + n;
    const float s  = sc[(size_t)g * N_DIM + nn];
    const int   zq = (qz[(size_t)g * WORDS_N + w0 + w] >> shf) & 0xF;
    const float nz = -(float)zq * s;

    #pragma unroll
    for (int oo = 0; oo < 2; ++oo) {
        const int oc = oc0 + oo * 4;
        const int4v lo = *(const int4v*)&Wq[w * WSTR + oc * 8];
        const int4v hi = *(const int4v*)&Wq[w * WSTR + oc * 8 + 4];
        f16x8 h;
        #pragma unroll
        for (int r = 0; r < 4; ++r)
            h[r] = (_Float16)((float)((lo[r] >> shf) & 0xF) * s + nz);
        #pragma unroll
        for (int r = 0; r < 4; ++r)
            h[4 + r] = (_Float16)((float)((hi[r] >> shf) & 0xF) * s + nz);
        const size_t kidx = (size_t)((k0 >> 3) + oc);
        Wf[((size_t)(nn >> 4) * 512 + kidx) * 16 + (nn & 15)] = h;
    }
}

// ---- main GEMM: 128M x 256N block, 4 waves each owning 128x64 (acc[8][4]).
//      Triple-buffered A (gload_lds+swizzle), ONE barrier per K-tile,
//      B double-buffered in regs from fragment-ordered Wf. ----
__global__ __launch_bounds__(256, 2)
void awq_gemm_pipe(const ushort* __restrict__ x16,
                   const f16x8* __restrict__ Wf,
                   const float* __restrict__ bias,
                   float* __restrict__ out,
                   int M, int nwg)
{
    __shared__ __align__(16) _Float16 As[3][128 * 64];  // 3 x 16 KB, A only

    const int tid  = threadIdx.x;
    const int lane = tid & 63;
    const int wid  = tid >> 6;

    // XCD swizzle: nwg divisible by 8; consecutive logical g share bx (B panel).
    const int hh  = blockIdx.x;
    const int g   = (hh & 7) * (nwg >> 3) + (hh >> 3);
    const int bx  = g >> 4;          // N tile (0..42)
    const int by  = g & 15;          // M tile (0..15)
    const int bn0 = bx * 256;
    const int bm0 = by * 128;

    const int wn0 = wid * 64;        // wave owns all 128 rows x 64 distinct cols

    // A staging: linear LDS dest, pre-swizzled global slot (proven round 10)
    const int srow = lane >> 3;
    const int slot = (lane & 7) ^ srow;
    const ushort* aSrc = x16 + (size_t)(bm0 + wid * 32 + srow) * K_DIM + slot * 8;

#define STAGE_A(BUFP, K0)                                                       \
    {                                                                           \
        _Pragma("unroll")                                                       \
        for (int jj = 0; jj < 4; ++jj)                                          \
            gload16(aSrc + (size_t)(K0) + jj * 8 * K_DIM,                       \
                    (BUFP) + (wid * 32 + jj * 8) * 64);                         \
    }

    // B fragment bases: unit idx = ntile*8192 + T*128 + ks*64 + lane
    size_t nb[4];
    #pragma unroll
    for (int n = 0; n < 4; ++n)
        nb[n] = ((size_t)((bn0 + wn0) >> 4) + n) * 8192 + lane;

    f32x4 acc[8][4];
    #pragma unroll
    for (int i = 0; i < 8; ++i)
        #pragma unroll
        for (int j = 0; j < 4; ++j)
            acc[i][j] = (f32x4){0.f, 0.f, 0.f, 0.f};

    f16x8 BR0[8], BR1[8];
    const int NT = K_DIM / 64;  // 64

#define LOADB(DST, T)                                                           \
    {                                                                           \
        const size_t koff = (size_t)(T) * 128;                                  \
        _Pragma("unroll")                                                       \
        for (int jj = 0; jj < 8; ++jj)                                          \
            DST[jj] = Wf[nb[jj & 3] + koff + (size_t)(jj >> 2) * 64];           \
    }

    const int rd_sw = (lane & 7) << 4;
    const int rrow  = lane & 15;

    // prologue: A0 -> buf0, B0 -> regs, A1 -> buf1 (issue order = vmcnt order)
    STAGE_A(&As[0][0], 0);
    LOADB(BR0, 0);
    STAGE_A(&As[1][0], 64);

    int rd = 0;   // buffer holding tile T (cycles 0,1,2)

    // ONE barrier per K-tile (proven round 13). STAGE_A at end of iter T writes
    // buf[(rd+2)%3], whose readers (iter T-1) all passed this iter's top barrier.
    // vmcnt(12) at top of T waits A(T); B regs are waited by compiler-inserted
    // dependencies. 12 newer loads in flight: B(T)8 + A(T+1)4.
#define ITER(T, BRD, BWR)                                                          \
    {                                                                              \
        asm volatile("s_waitcnt vmcnt(12)" ::: "memory");                          \
        __builtin_amdgcn_sched_barrier(0);                                         \
        __builtin_amdgcn_s_barrier();                                              \
        __builtin_amdgcn_sched_barrier(0);                                         \
        { const int tn = ((T) + 1 < NT) ? (T) + 1 : NT - 1; LOADB(BWR, tn); }      \
        __builtin_amdgcn_sched_barrier(0);                                         \
        const char* aB = (const char*)&As[rd][0];                                  \
        _Pragma("unroll")                                                          \
        for (int ks = 0; ks < 2; ++ks) {                                           \
            const int kb = ks * 64 + ((lane >> 4) << 4);                           \
            __builtin_amdgcn_s_setprio(1);                                         \
            _Pragma("unroll")                                                      \
            for (int m = 0; m < 8; ++m) {                                          \
                f16x8 af = *(const f16x8*)(aB + (m * 16 + rrow) * 128 + (kb ^ rd_sw)); \
                _Pragma("unroll")                                                  \
                for (int n = 0; n < 4; ++n)                                        \
                    acc[m][n] = __builtin_amdgcn_mfma_f32_16x16x32_f16(            \
                        af, BRD[ks * 4 + n], acc[m][n], 0, 0, 0);                  \
            }                                                                      \
            __builtin_amdgcn_s_setprio(0);                                         \
        }                                                                          \
        {                                                                          \
            const int stg = (rd >= 1) ? rd - 1 : 2;        /* (rd+2)%3 */          \
            const int t2  = ((T) + 2 < NT) ? (T) + 2 : NT - 1;                     \
            STAGE_A(&As[stg][0], t2 * 64);                                         \
        }                                                                          \
        rd = (rd < 2) ? rd + 1 : 0;                                                \
    }

    for (int t = 0; t < NT; t += 2) {
        ITER(t,     BR0, BR1);
        ITER(t + 1, BR1, BR0);
    }
#undef ITER
#undef LOADB
#undef STAGE_A

    // epilogue: C/D col=lane&15, row=(lane>>4)*4+r (m89-verified)
    #pragma unroll
    for (int n = 0; n < 4; ++n) {
        const int col = bn0 + wn0 + n * 16 + (lane & 15);
        const float b_f = bias[col];
        #pragma unroll
        for (int m = 0; m < 8; ++m) {
            const int row_base = bm0 + m * 16 + ((lane >> 4) << 2);
            #pragma unroll
            for (int r = 0; r < 4; ++r) {
                const int row = row_base + r;
                if (row < M)
                    out[(size_t)row * N_DIM + col] = acc[m][n][r] + b_f;
            }
        }
    }
}

// ---- fallback: fused kernel (proven rounds 6-8) ----
template <bool XF16>
__global__ __launch_bounds__(256, 2)
void awq_gemm_fused(const void* __restrict__ xin,
                    const int* __restrict__ qw,
                    const int* __restrict__ qz,
                    const float* __restrict__ sc,
                    const float* __restrict__ bias,
                    float* __restrict__ out,
                    int M)
{
    __shared__ __align__(16) _Float16 Asf[BM * ASTR];
    __shared__ __align__(16) int Wq[32 * WSTR];

    const int tid  = threadIdx.x;
    const int lane = tid & 63;
    const int wid  = tid >> 6;
    const int bn0 = blockIdx.x * BN;
    const int bm0 = blockIdx.y * BM;
    const int w0  = bn0 >> 3;
    const int wn0 = wid * 64;
    const int a_row = tid >> 3;
    const int a_col = (tid & 7) * 8;
    const int b_krow = tid >> 2;
    const int b_wg   = (tid & 3) * 4;

    int n_loc[4], w_loc[4], shf[4];
    #pragma unroll
    for (int bn = 0; bn < 4; ++bn) {
        n_loc[bn] = wn0 + bn * 16 + (lane & 15);
        w_loc[bn] = n_loc[bn] >> 3;
        int j = n_loc[bn] & 7;
        shf[bn] = ((j & 1) << 4) + ((j >> 1) << 2);
    }
    f16x2 s2[4], c2[4];
    f32x4 acc[8][4];
    #pragma unroll
    for (int i = 0; i < 8; ++i)
        #pragma unroll
        for (int j = 0; j < 4; ++j)
            acc[i][j] = (f32x4){0.f, 0.f, 0.f, 0.f};
    int4v aReg16[4];
    f32x8 aReg32[4];
    int4v bReg[2];
    const ushort* x16 = (const ushort*)xin;
    const float*  x32 = (const float*)xin;

#define LOAD_TILE(K0)                                                                  \
    {                                                                                  \
        _Pragma("unroll")                                                              \
        for (int i = 0; i < 4; ++i) {                                                  \
            int row = bm0 + a_row + i * 32;                                            \
            if constexpr (XF16) {                                                      \
                if (row < M)                                                           \
                    aReg16[i] = *(const int4v*)(x16 + (size_t)row * K_DIM + (K0) + a_col); \
                else aReg16[i] = (int4v){0, 0, 0, 0};                                  \
            } else {                                                                   \
                if (row < M)                                                           \
                    aReg32[i] = *(const f32x8*)(x32 + (size_t)row * K_DIM + (K0) + a_col); \
                else aReg32[i] = (f32x8){0.f,0.f,0.f,0.f,0.f,0.f,0.f,0.f};             \
            }                                                                          \
        }                                                                              \
        bReg[0] = *(const int4v*)(qw + (size_t)((K0) + b_krow) * WORDS_N + w0 + b_wg);      \
        bReg[1] = *(const int4v*)(qw + (size_t)((K0) + b_krow) * WORDS_N + w0 + b_wg + 16); \
    }

    LOAD_TILE(0);
    const int NT = K_DIM / BK;
    for (int t = 0; t < NT; ++t) {
        const int k0 = t * BK;
        __syncthreads();
        #pragma unroll
        for (int i = 0; i < 4; ++i) {
            if constexpr (XF16) {
                *(int4v*)&Asf[(a_row + i * 32) * ASTR + a_col] = aReg16[i];
            } else {
                f16x8 hh2;
                #pragma unroll
                for (int r = 0; r < 4; ++r) {
                    f16x2 p = __builtin_bit_cast(f16x2,
                        __builtin_amdgcn_cvt_pkrtz(aReg32[i][2*r], aReg32[i][2*r+1]));
                    hh2[2*r] = p[0]; hh2[2*r+1] = p[1];
                }
                *(f16x8*)&Asf[(a_row + i * 32) * ASTR + a_col] = hh2;
            }
        }
        #pragma unroll
        for (int c = 0; c < 4; ++c) {
            Wq[(b_wg + c) * WSTR + b_krow]      = bReg[0][c];
            Wq[(b_wg + 16 + c) * WSTR + b_krow] = bReg[1][c];
        }
        __syncthreads();
        if (t + 1 < NT) LOAD_TILE(k0 + BK);
        if ((t & 1) == 0) {
            const int gg = k0 >> 7;
            #pragma unroll
            for (int bn = 0; bn < 4; ++bn) {
                float s = sc[(size_t)gg * N_DIM + bn0 + n_loc[bn]];
                int zq  = (qz[(size_t)gg * WORDS_N + w0 + w_loc[bn]] >> shf[bn]) & 0xF;
                _Float16 sh = (_Float16)s;
                _Float16 nz = (_Float16)(-(float)zq * s);
                s2[bn] = (f16x2){sh, sh};
                c2[bn] = (f16x2){nz, nz};
            }
        }
        #pragma unroll
        for (int ks = 0; ks < 2; ++ks) {
            const int kk = ks * 32 + (lane >> 4) * 8;
            f16x8 af[8];
            #pragma unroll
            for (int am = 0; am < 8; ++am)
                af[am] = *(const f16x8*)&Asf[(am * 16 + (lane & 15)) * ASTR + kk];
            #pragma unroll
            for (int bn = 0; bn < 4; ++bn) {
                const int4v lo = *(const int4v*)&Wq[w_loc[bn] * WSTR + kk];
                const int4v hi = *(const int4v*)&Wq[w_loc[bn] * WSTR + kk + 4];
                f16x8 bfr;
                f16x2 p;
                p = dq2(lo[0], lo[1], shf[bn], s2[bn], c2[bn]); bfr[0]=p[0]; bfr[1]=p[1];
                p = dq2(lo[2], lo[3], shf[bn], s2[bn], c2[bn]); bfr[2]=p[0]; bfr[3]=p[1];
                p = dq2(hi[0], hi[1], shf[bn], s2[bn], c2[bn]); bfr[4]=p[0]; bfr[5]=p[1];
                p = dq2(hi[2], hi[3], shf[bn], s2[bn], c2[bn]); bfr[6]=p[0]; bfr[7]=p[1];
                #pragma unroll
                for (int am = 0; am < 8; ++am)
                    acc[am][bn] = __builtin_amdgcn_mfma_f32_16x16x32_f16(
                        af[am], bfr, acc[am][bn], 0, 0, 0);
            }
        }
    }
    #pragma unroll
    for (int bn = 0; bn < 4; ++bn) {
        const int col = bn0 + wn0 + bn * 16 + (lane & 15);
        const float b_f = bias[col];
        #pragma unroll
        for (int am = 0; am < 8; ++am) {
            const int row_base = bm0 + am * 16 + ((lane >> 4) << 2);
            #pragma unroll
            for (int r = 0; r < 4; ++r) {
                const int row = row_base + r;
                if (row < M)
                    out[(size_t)row * N_DIM + col] = acc[am][bn][r] + b_f;
            }
        }
    }
#undef LOAD_TILE
}

extern "C" void kernel_launch(void* const* d_in, const int* in_sizes, int n_in,
                              void* d_out, int out_size, void* d_ws, size_t ws_size,
                              hipStream_t stream) {
    const float* x    = (const float*)d_in[0];
    const int*   qw   = (const int*)d_in[1];
    const int*   qz   = (const int*)d_in[2];
    const float* sc   = (const float*)d_in[3];
    const float* bias = (const float*)d_in[4];
    float*       out  = (float*)d_out;

    const int M = in_sizes[0] / K_DIM;
    const size_t x_bytes = (size_t)M * K_DIM * 2;
    const size_t w_bytes = (size_t)N_DIM * K_DIM * 2;

    if (ws_size >= x_bytes + w_bytes && (M % 128) == 0) {
        ushort* xf = (ushort*)d_ws;
        f16x8*  Wf = (f16x8*)((char*)d_ws + x_bytes);
        cvt_x_kernel<<<dim3(2048), dim3(256), 0, stream>>>(x, xf, (M * K_DIM) / 8);
        dequant_w_kernel<<<dim3(WORDS_N / 8, K_DIM / 64), dim3(256), 0, stream>>>(qw, qz, sc, Wf);
        const int nwg = (N_DIM / 256) * (M / 128);   // 43 x 16 = 688, %8==0
        awq_gemm_pipe<<<dim3(nwg), dim3(256), 0, stream>>>(xf, Wf, bias, out, M, nwg);
    } else if (ws_size >= x_bytes) {
        ushort* xf = (ushort*)d_ws;
        const int mtiles = (M + BM - 1) / BM;
        cvt_x_kernel<<<dim3(2048), dim3(256), 0, stream>>>(x, xf, (M * K_DIM) / 8);
        awq_gemm_fused<true><<<dim3(N_DIM / BN, mtiles), dim3(256), 0, stream>>>(
            xf, qw, qz, sc, bias, out, M);
    } else {
        const int mtiles = (M + BM - 1) / BM;
        awq_gemm_fused<false><<<dim3(N_DIM / BN, mtiles), dim3(256), 0, stream>>>(
            x, qw, qz, sc, bias, out, M);
    }
}